// Round 8
// baseline (1264.427 us; speedup 1.0000x reference)
//
#include <hip/hip_runtime.h>

#define D 128
#define SCAN_BLK 1024
#define BM 64
#define KC 32
#define BSH 6            // bucket shift: 64 nodes per bucket
#define BNODES 64

using short8 = __attribute__((ext_vector_type(8))) short;
using floatx4 = __attribute__((ext_vector_type(4))) float;

__device__ __forceinline__ unsigned int f2bf(unsigned int b) {
    return (b + 0x7fffu + ((b >> 16) & 1u)) >> 16;  // RNE fp32->bf16 (as u16)
}

// ---------- W transpose (tier-3 VALU path) ----------
__global__ void transpose_w_kernel(const float* __restrict__ w, float* __restrict__ wt) {
    int t = blockIdx.x * 256 + threadIdx.x;
    if (t < D * D) {
        int o = t >> 7;
        int k = t & 127;
        wt[k * D + o] = w[t];
    }
}

// ---------- W -> bf16, XOR-swizzled [n][k] table for MFMA B-frags ----------
__global__ void prep_wbfs_kernel(const float* __restrict__ w, unsigned short* __restrict__ wbfs) {
    int t = blockIdx.x * 256 + threadIdx.x;
    if (t < D * D) {
        int n = t >> 7, k = t & 127;
        wbfs[n * 128 + (k ^ ((n & 7) << 3))] = (unsigned short)f2bf(__float_as_uint(w[t]));
    }
}

// ---------- x -> bf16 SPLIT packing: xbf[n*64+q] = bf16(x[n][q]) | bf16(x[n][q+64])<<16
// (lane q ds_adds ch q and q+64 -> stride-1 LDS words, conflict-free)
__global__ __launch_bounds__(256) void x_to_bf16_split_kernel(const float* __restrict__ x,
                                                              unsigned int* __restrict__ xbf,
                                                              long long ngrp /* N*16 */) {
    long long g = (long long)blockIdx.x * 256 + threadIdx.x;
    long long stride = (long long)gridDim.x * 256;
    for (; g < ngrp; g += stride) {
        long long i = g * 4;                 // uint index, q = i&63 multiple of 4
        long long node = i >> 6;
        int q = (int)(i & 63);
        const float* row = x + node * D;
        float4 lo = *(const float4*)&row[q];
        float4 hi = *(const float4*)&row[q + 64];
        uint4 o;
        o.x = f2bf(__float_as_uint(lo.x)) | (f2bf(__float_as_uint(hi.x)) << 16);
        o.y = f2bf(__float_as_uint(lo.y)) | (f2bf(__float_as_uint(hi.y)) << 16);
        o.z = f2bf(__float_as_uint(lo.z)) | (f2bf(__float_as_uint(hi.z)) << 16);
        o.w = f2bf(__float_as_uint(lo.w)) | (f2bf(__float_as_uint(hi.w)) << 16);
        *(uint4*)&xbf[i] = o;
    }
}

// ---------- x -> bf16 PAIR packing (fallback gather path) ----------
__global__ __launch_bounds__(256) void x_to_bf16_kernel(const float* __restrict__ x,
                                                        unsigned int* __restrict__ xbf,
                                                        long long nvec) {
    long long i = (long long)blockIdx.x * 256 + threadIdx.x;
    long long stride = (long long)gridDim.x * 256;
    for (; i < nvec; i += stride) {
        float4 v = ((const float4*)x)[i];
        unsigned int b0 = f2bf(__float_as_uint(v.x)), b1 = f2bf(__float_as_uint(v.y));
        unsigned int b2 = f2bf(__float_as_uint(v.z)), b3 = f2bf(__float_as_uint(v.w));
        ((uint2*)xbf)[i] = make_uint2(b0 | (b1 << 16), b2 | (b3 << 16));
    }
}

// ---------- bucket histogram (64-node buckets) ----------
__global__ __launch_bounds__(512) void bhist_kernel(const int* __restrict__ ei, int* bhist,
                                                    int E, int NB) {
    __shared__ int h[2048];
    int tid = threadIdx.x;
    for (int i = tid; i < NB; i += 512) h[i] = 0;
    __syncthreads();
    for (long long e = (long long)blockIdx.x * 512 + tid; e < E; e += (long long)gridDim.x * 512)
        atomicAdd(&h[((unsigned)ei[e]) >> BSH], 1);
    __syncthreads();
    for (int i = tid; i < NB; i += 512)
        if (h[i]) atomicAdd(&bhist[i], h[i]);
}

// ---------- scans (generic, reused for bucket scan + fallback node scan) ----------
__global__ __launch_bounds__(SCAN_BLK) void scan_blocks_kernel(const int* __restrict__ deg,
                                                               int* inscan, int* blksum, int n) {
    __shared__ int s[SCAN_BLK];
    int gid = blockIdx.x * SCAN_BLK + threadIdx.x;
    int v = (gid < n) ? deg[gid] : 0;
    s[threadIdx.x] = v;
    __syncthreads();
    for (int d = 1; d < SCAN_BLK; d <<= 1) {
        int t = (threadIdx.x >= d) ? s[threadIdx.x - d] : 0;
        __syncthreads();
        s[threadIdx.x] += t;
        __syncthreads();
    }
    if (gid < n) inscan[gid] = s[threadIdx.x];
    if (threadIdx.x == SCAN_BLK - 1) blksum[blockIdx.x] = s[SCAN_BLK - 1];
}

__global__ __launch_bounds__(128) void scan_sums_kernel(const int* __restrict__ blksum,
                                                        int* blkoff, int nblk) {
    __shared__ int s[128];
    int v = (threadIdx.x < nblk) ? blksum[threadIdx.x] : 0;
    s[threadIdx.x] = v;
    __syncthreads();
    for (int d = 1; d < 128; d <<= 1) {
        int t = (threadIdx.x >= d) ? s[threadIdx.x - d] : 0;
        __syncthreads();
        s[threadIdx.x] += t;
        __syncthreads();
    }
    if (threadIdx.x < nblk) blkoff[threadIdx.x] = s[threadIdx.x] - v;
}

__global__ void bucket_finalize_kernel(const int* __restrict__ bhist,
                                       const int* __restrict__ binscan,
                                       const int* __restrict__ bblkoff,
                                       int* bbase, int* bcursor, int NB, int E) {
    int g = blockIdx.x * 256 + threadIdx.x;
    if (g < NB) {
        int o = bblkoff[g >> 10] + binscan[g] - bhist[g];  // exclusive
        bbase[g] = o;
        bcursor[g] = o;
    }
    if (g == 0) bbase[NB] = E;
}

// ---------- binA: partition edges into 64-node buckets (order-free) ----------
// pack: src (26b) | dst_local (6b) << 26
__global__ __launch_bounds__(512) void binA_kernel(const int* __restrict__ ei,
                                                   const float* __restrict__ ev,
                                                   int* bcursor, int2* __restrict__ ebin,
                                                   int E, int NB) {
    __shared__ int hist[2048];
    __shared__ int base[2048];
    __shared__ int cnt2[2048];
    int tid = threadIdx.x;
    for (int i = tid; i < NB; i += 512) { hist[i] = 0; cnt2[i] = 0; }
    __syncthreads();
    int e0 = blockIdx.x * 8192;
#pragma unroll
    for (int i = 0; i < 16; ++i) {
        int e = e0 + i * 512 + tid;
        if (e < E) atomicAdd(&hist[((unsigned)ei[e]) >> BSH], 1);
    }
    __syncthreads();
    for (int i = tid; i < NB; i += 512)
        if (hist[i]) base[i] = atomicAdd(&bcursor[i], hist[i]);
    __syncthreads();
#pragma unroll
    for (int i = 0; i < 16; ++i) {
        int e = e0 + i * 512 + tid;
        if (e < E) {
            int dst = ei[e];
            int b = ((unsigned)dst) >> BSH;
            int pos = base[b] + atomicAdd(&cnt2[b], 1);
            ebin[pos] = make_int2(ei[E + e] | ((dst & (BNODES - 1)) << 26),
                                  __float_as_int(ev[e]));
        }
    }
}

// ---------- fused bin-gather: LDS out-tile + ds_add_f32, flush packed bf16 ----------
__global__ __launch_bounds__(512) void gather_bin_kernel(const int* __restrict__ bbase,
                                                         const int2* __restrict__ ebin,
                                                         const unsigned int* __restrict__ xbf,
                                                         unsigned int* __restrict__ aggbf,
                                                         int N) {
    __shared__ float tile[BNODES * D];  // 32 KiB, [node_local][ch]
    int b = blockIdx.x;
    int tid = threadIdx.x;
    int lane = tid & 63;
    for (int i = tid; i < BNODES * D / 4; i += 512)
        ((float4*)tile)[i] = make_float4(0.f, 0.f, 0.f, 0.f);
    __syncthreads();

    int start = bbase[b], end = bbase[b + 1];
    int cnt = end - start;
    if (cnt > 0) {
        int wid = tid >> 6;
        int per = (cnt + 7) >> 3;
        int wbeg = start + wid * per;
        int wend = wbeg + per < end ? wbeg + per : end;
        int e = wbeg;
        for (; e + 3 < wend; e += 4) {
            int2 b0 = ebin[e], b1 = ebin[e + 1], b2 = ebin[e + 2], b3 = ebin[e + 3];
            unsigned int u0 = xbf[(size_t)(b0.x & 0x03FFFFFF) * 64 + lane];
            unsigned int u1 = xbf[(size_t)(b1.x & 0x03FFFFFF) * 64 + lane];
            unsigned int u2 = xbf[(size_t)(b2.x & 0x03FFFFFF) * 64 + lane];
            unsigned int u3 = xbf[(size_t)(b3.x & 0x03FFFFFF) * 64 + lane];
            int d0 = ((unsigned)b0.x) >> 26, d1 = ((unsigned)b1.x) >> 26;
            int d2 = ((unsigned)b2.x) >> 26, d3 = ((unsigned)b3.x) >> 26;
            float v0 = __int_as_float(b0.y), v1 = __int_as_float(b1.y);
            float v2 = __int_as_float(b2.y), v3 = __int_as_float(b3.y);
            // lane handles ch `lane` (lo) and `lane+64` (hi): stride-1 words, no conflict
            atomicAdd(&tile[d0 * D + lane], v0 * __uint_as_float(u0 << 16));
            atomicAdd(&tile[d0 * D + 64 + lane], v0 * __uint_as_float(u0 & 0xffff0000u));
            atomicAdd(&tile[d1 * D + lane], v1 * __uint_as_float(u1 << 16));
            atomicAdd(&tile[d1 * D + 64 + lane], v1 * __uint_as_float(u1 & 0xffff0000u));
            atomicAdd(&tile[d2 * D + lane], v2 * __uint_as_float(u2 << 16));
            atomicAdd(&tile[d2 * D + 64 + lane], v2 * __uint_as_float(u2 & 0xffff0000u));
            atomicAdd(&tile[d3 * D + lane], v3 * __uint_as_float(u3 << 16));
            atomicAdd(&tile[d3 * D + 64 + lane], v3 * __uint_as_float(u3 & 0xffff0000u));
        }
        for (; e < wend; ++e) {
            int2 eb = ebin[e];
            unsigned int u = xbf[(size_t)(eb.x & 0x03FFFFFF) * 64 + lane];
            int dl = ((unsigned)eb.x) >> 26;
            float v = __int_as_float(eb.y);
            atomicAdd(&tile[dl * D + lane], v * __uint_as_float(u << 16));
            atomicAdd(&tile[dl * D + 64 + lane], v * __uint_as_float(u & 0xffff0000u));
        }
    }
    __syncthreads();

    // flush: pack pairs (2q,2q+1) -> aggbf (k-contiguous for linear_mfma_bf)
    int node0 = b << BSH;
    for (int i = tid; i < BNODES * 64; i += 512) {
        int nl = i >> 6, q = i & 63;
        int node = node0 + nl;
        if (node < N) {
            float lo = tile[nl * D + 2 * q];
            float hi = tile[nl * D + 2 * q + 1];
            aggbf[(size_t)node * 64 + q] =
                f2bf(__float_as_uint(lo)) | (f2bf(__float_as_uint(hi)) << 16);
        }
    }
}

// ---------- fallback CSR machinery ----------
__global__ void hist_rank_kernel(const int* __restrict__ ei, int* deg,
                                 unsigned short* __restrict__ rank, int E) {
    int e = blockIdx.x * 256 + threadIdx.x;
    if (e < E) rank[e] = (unsigned short)atomicAdd(&deg[ei[e]], 1);
}

__global__ void finalize_offsets_kernel(const int* __restrict__ deg,
                                        const int* __restrict__ inscan,
                                        const int* __restrict__ blkoff,
                                        int* off, int n, int E) {
    int gid = blockIdx.x * 256 + threadIdx.x;
    if (gid < n) off[gid] = blkoff[gid >> 10] + inscan[gid] - deg[gid];
    if (gid == 0) off[n] = E;
}

__global__ void edge_scatter2_kernel(const int* __restrict__ ei, const float* __restrict__ ev,
                                     const int* __restrict__ off,
                                     const unsigned short* __restrict__ rank,
                                     int2* __restrict__ srt, int E) {
    int e = blockIdx.x * 256 + threadIdx.x;
    if (e < E) {
        int dst = ei[e];
        int pos = off[dst] + (int)rank[e];
        srt[pos] = make_int2(ei[E + e], __float_as_int(ev[e]));
    }
}

// fallback gather (PAIR-packed xbf), writes fp32 out
__global__ __launch_bounds__(256) void gather_bf16_kernel(const int* __restrict__ off,
                                                          const int2* __restrict__ srt,
                                                          const unsigned int* __restrict__ xbf,
                                                          float* __restrict__ out, int N) {
    int lane = threadIdx.x & 63;
    int wid = blockIdx.x * 4 + (threadIdx.x >> 6);
    if (wid >= N) return;
    int beg = off[wid], end = off[wid + 1];
    float2 acc = make_float2(0.f, 0.f);
    int e = beg;
    for (; e + 3 < end; e += 4) {
        int2 s0 = srt[e], s1 = srt[e + 1], s2 = srt[e + 2], s3 = srt[e + 3];
        unsigned int u0 = xbf[(size_t)s0.x * 64 + lane];
        unsigned int u1 = xbf[(size_t)s1.x * 64 + lane];
        unsigned int u2 = xbf[(size_t)s2.x * 64 + lane];
        unsigned int u3 = xbf[(size_t)s3.x * 64 + lane];
        float v0 = __int_as_float(s0.y), v1 = __int_as_float(s1.y);
        float v2 = __int_as_float(s2.y), v3 = __int_as_float(s3.y);
        acc.x = fmaf(v0, __uint_as_float(u0 << 16), acc.x);
        acc.y = fmaf(v0, __uint_as_float(u0 & 0xffff0000u), acc.y);
        acc.x = fmaf(v1, __uint_as_float(u1 << 16), acc.x);
        acc.y = fmaf(v1, __uint_as_float(u1 & 0xffff0000u), acc.y);
        acc.x = fmaf(v2, __uint_as_float(u2 << 16), acc.x);
        acc.y = fmaf(v2, __uint_as_float(u2 & 0xffff0000u), acc.y);
        acc.x = fmaf(v3, __uint_as_float(u3 << 16), acc.x);
        acc.y = fmaf(v3, __uint_as_float(u3 & 0xffff0000u), acc.y);
    }
    for (; e < end; ++e) {
        int2 sv = srt[e];
        unsigned int u = xbf[(size_t)sv.x * 64 + lane];
        float v = __int_as_float(sv.y);
        acc.x = fmaf(v, __uint_as_float(u << 16), acc.x);
        acc.y = fmaf(v, __uint_as_float(u & 0xffff0000u), acc.y);
    }
    *(float2*)&out[(size_t)wid * D + lane * 2] = acc;
}

// ---------- MFMA linear, A from packed-bf16 agg -> writes d_out ----------
__global__ __launch_bounds__(256) void linear_mfma_bf_kernel(const unsigned int* __restrict__ aggbf,
                                                             const unsigned short* __restrict__ wbfs,
                                                             float* __restrict__ out, int N) {
    __shared__ __align__(16) unsigned short sW[D * D];
    __shared__ __align__(16) unsigned short sA[BM * D];
    int t = threadIdx.x;
    int row0 = blockIdx.x * BM;
    {
        const uint4* src = (const uint4*)wbfs;
        uint4* dst = (uint4*)sW;
#pragma unroll
        for (int i = 0; i < 8; ++i) dst[i * 256 + t] = src[i * 256 + t];
    }
#pragma unroll
    for (int it = 0; it < 4; ++it) {
        int iv = it * 256 + t;
        int m = iv >> 4;
        int q = iv & 15;
        int r = row0 + m;
        int rcl = r < N ? r : N - 1;
        uint4 v = *(const uint4*)&aggbf[(size_t)rcl * 64 + q * 4];
        *(uint4*)((char*)sA + m * 256 + ((q * 16) ^ ((m & 7) << 4))) = v;
    }
    __syncthreads();

    int lane = t & 63;
    int w = t >> 6;
    int lm = 16 * w + (lane & 15);
    int ln = lane & 15;
    int kg = lane >> 4;

    floatx4 acc[8];
#pragma unroll
    for (int nt = 0; nt < 8; ++nt) acc[nt] = (floatx4){0.f, 0.f, 0.f, 0.f};

#pragma unroll
    for (int ks = 0; ks < 4; ++ks) {
        int kbyte = ks * 64 + kg * 16;
        short8 a = *(const short8*)((const char*)sA + lm * 256 + (kbyte ^ ((lm & 7) << 4)));
#pragma unroll
        for (int nt = 0; nt < 8; ++nt) {
            int n = nt * 16 + ln;
            short8 bfr = *(const short8*)((const char*)sW + n * 256 + (kbyte ^ ((n & 7) << 4)));
            acc[nt] = __builtin_amdgcn_mfma_f32_16x16x32_bf16(a, bfr, acc[nt], 0, 0, 0);
        }
    }

    int rbase = row0 + 16 * w + 4 * kg;
#pragma unroll
    for (int nt = 0; nt < 8; ++nt) {
#pragma unroll
        for (int r = 0; r < 4; ++r) {
            int row = rbase + r;
            if (row < N) out[(size_t)row * D + nt * 16 + ln] = acc[nt][r];
        }
    }
}

// ---------- MFMA linear in-place from fp32 io (fallback) ----------
__global__ __launch_bounds__(256) void linear_mfma_kernel(float* io,
                                                          const unsigned short* __restrict__ wbfs,
                                                          int N) {
    __shared__ __align__(16) unsigned short sW[D * D];
    __shared__ __align__(16) unsigned short sA[BM * D];
    int t = threadIdx.x;
    int row0 = blockIdx.x * BM;
    {
        const uint4* src = (const uint4*)wbfs;
        uint4* dst = (uint4*)sW;
#pragma unroll
        for (int i = 0; i < 8; ++i) dst[i * 256 + t] = src[i * 256 + t];
    }
#pragma unroll
    for (int it = 0; it < 8; ++it) {
        int idx = it * 1024 + t * 4;
        int m = idx >> 7;
        int k0 = idx & 127;
        int r = row0 + m;
        int rcl = r < N ? r : N - 1;
        float4 v = *(const float4*)&io[(size_t)rcl * D + k0];
        unsigned int b0 = f2bf(__float_as_uint(v.x)), b1 = f2bf(__float_as_uint(v.y));
        unsigned int b2 = f2bf(__float_as_uint(v.z)), b3 = f2bf(__float_as_uint(v.w));
        int byteoff = m * 256 + ((k0 * 2) ^ ((m & 7) << 4));
        *(uint2*)((char*)sA + byteoff) = make_uint2(b0 | (b1 << 16), b2 | (b3 << 16));
    }
    __syncthreads();

    int lane = t & 63;
    int w = t >> 6;
    int lm = 16 * w + (lane & 15);
    int ln = lane & 15;
    int kg = lane >> 4;

    floatx4 acc[8];
#pragma unroll
    for (int nt = 0; nt < 8; ++nt) acc[nt] = (floatx4){0.f, 0.f, 0.f, 0.f};

#pragma unroll
    for (int ks = 0; ks < 4; ++ks) {
        int kbyte = ks * 64 + kg * 16;
        short8 a = *(const short8*)((const char*)sA + lm * 256 + (kbyte ^ ((lm & 7) << 4)));
#pragma unroll
        for (int nt = 0; nt < 8; ++nt) {
            int n = nt * 16 + ln;
            short8 bfr = *(const short8*)((const char*)sW + n * 256 + (kbyte ^ ((n & 7) << 4)));
            acc[nt] = __builtin_amdgcn_mfma_f32_16x16x32_bf16(a, bfr, acc[nt], 0, 0, 0);
        }
    }

    int rbase = row0 + 16 * w + 4 * kg;
#pragma unroll
    for (int nt = 0; nt < 8; ++nt) {
#pragma unroll
        for (int r = 0; r < 4; ++r) {
            int row = rbase + r;
            if (row < N) io[(size_t)row * D + nt * 16 + ln] = acc[nt][r];
        }
    }
}

// ---------- tier-3 fallbacks ----------
__global__ __launch_bounds__(256) void scatter_kernel(const int* __restrict__ ei,
                                                      const float* __restrict__ ev,
                                                      const float* __restrict__ x,
                                                      float* agg, int E) {
    int lane = threadIdx.x & 63;
    long long wid = (long long)blockIdx.x * 4 + (threadIdx.x >> 6);
    long long nw = (long long)gridDim.x * 4;
    for (long long e = wid; e < E; e += nw) {
        int i = ei[e];
        int j = ei[(long long)E + e];
        float v = ev[e];
        float2 xv = *(const float2*)&x[(size_t)j * D + lane * 2];
        float* op = &agg[(size_t)i * D + lane * 2];
        unsafeAtomicAdd(&op[0], v * xv.x);
        unsafeAtomicAdd(&op[1], v * xv.y);
    }
}

__global__ __launch_bounds__(256) void linear_tiled_kernel(float* io,
                                                           const float* __restrict__ wt,
                                                           int N) {
    __shared__ float sA[KC][BM + 4];
    __shared__ float sW2[KC][D];
    int t = threadIdx.x;
    int tc = t & 15;
    int tr = t >> 4;
    int row0 = blockIdx.x * BM;

    float acc[4][8];
#pragma unroll
    for (int i = 0; i < 4; ++i)
#pragma unroll
        for (int j = 0; j < 8; ++j) acc[i][j] = 0.f;

    int ldA_r = t >> 3;
    int ldA_k = (t & 7) * 4;
    int ldW_k = t >> 5;
    int ldW_c = (t & 31) * 4;

    for (int kc = 0; kc < D; kc += KC) {
#pragma unroll
        for (int rr = 0; rr < BM; rr += 32) {
            int r = row0 + ldA_r + rr;
            int rcl = r < N ? r : N - 1;
            float4 v = *(const float4*)&io[(size_t)rcl * D + kc + ldA_k];
            sA[ldA_k + 0][ldA_r + rr] = v.x;
            sA[ldA_k + 1][ldA_r + rr] = v.y;
            sA[ldA_k + 2][ldA_r + rr] = v.z;
            sA[ldA_k + 3][ldA_r + rr] = v.w;
        }
#pragma unroll
        for (int kk = 0; kk < KC; kk += 8)
            *(float4*)&sW2[ldW_k + kk][ldW_c] =
                *(const float4*)&wt[(size_t)(kc + ldW_k + kk) * D + ldW_c];
        __syncthreads();

#pragma unroll 8
        for (int k = 0; k < KC; ++k) {
            float4 a = *(const float4*)&sA[k][tr * 4];
            float4 w0 = *(const float4*)&sW2[k][tc * 8];
            float4 w1 = *(const float4*)&sW2[k][tc * 8 + 4];
            float av[4] = {a.x, a.y, a.z, a.w};
            float wv[8] = {w0.x, w0.y, w0.z, w0.w, w1.x, w1.y, w1.z, w1.w};
#pragma unroll
            for (int i = 0; i < 4; ++i)
#pragma unroll
                for (int j = 0; j < 8; ++j)
                    acc[i][j] = fmaf(av[i], wv[j], acc[i][j]);
        }
        __syncthreads();
    }

#pragma unroll
    for (int i = 0; i < 4; ++i) {
        int r = row0 + tr * 4 + i;
        if (r < N) {
            *(float4*)&io[(size_t)r * D + tc * 8] = *(float4*)&acc[i][0];
            *(float4*)&io[(size_t)r * D + tc * 8 + 4] = *(float4*)&acc[i][4];
        }
    }
}

extern "C" void kernel_launch(void* const* d_in, const int* in_sizes, int n_in,
                              void* d_out, int out_size, void* d_ws, size_t ws_size,
                              hipStream_t stream) {
    const float* x = (const float*)d_in[0];
    const float* w = (const float*)d_in[1];
    const int* ei = (const int*)d_in[2];   // [2,E] int32 (dst row, then src row)
    const float* ev = (const float*)d_in[3];

    int N = in_sizes[0] / D;
    int E = in_sizes[3];
    int nblk = (N + SCAN_BLK - 1) / SCAN_BLK;
    int NB = (N + BNODES - 1) >> BSH;          // 64-node buckets
    int nblkB = (NB + SCAN_BLK - 1) / SCAN_BLK;

    float* out = (float*)d_out;

    // workspace layout
    char* p = (char*)d_ws;
    float* wt = (float*)p;            p += (size_t)D * D * sizeof(float);
    unsigned short* wbfs = (unsigned short*)p;  p += (size_t)D * D * sizeof(unsigned short);
    int* deg = (int*)p;               p += (size_t)N * sizeof(int);
    int* inscan = (int*)p;            p += (size_t)N * sizeof(int);
    int* off = (int*)p;               p += (size_t)(N + 1) * sizeof(int);
    int* blksum = (int*)p;            p += (size_t)nblk * sizeof(int);
    int* blkoff = (int*)p;            p += (size_t)nblk * sizeof(int);
    p = (char*)(((uintptr_t)p + 255) & ~(uintptr_t)255);
    unsigned short* rank = (unsigned short*)p;  p += (size_t)E * sizeof(unsigned short);
    p = (char*)(((uintptr_t)p + 255) & ~(uintptr_t)255);
    int2* srt = (int2*)p;             p += (size_t)E * sizeof(int2);
    size_t needed_t2 = (size_t)(p - (char*)d_ws);
    p = (char*)(((uintptr_t)p + 255) & ~(uintptr_t)255);
    unsigned int* xbf = (unsigned int*)p;  p += (size_t)N * (D / 2) * sizeof(unsigned int);
    size_t needed_t1 = (size_t)(p - (char*)d_ws);
    p = (char*)(((uintptr_t)p + 255) & ~(uintptr_t)255);
    int2* ebin = (int2*)p;            p += (size_t)E * sizeof(int2);
    p = (char*)(((uintptr_t)p + 255) & ~(uintptr_t)255);
    unsigned int* aggbf = (unsigned int*)p;  p += (size_t)N * (D / 2) * sizeof(unsigned int);
    int* bhist = (int*)p;             p += (size_t)NB * sizeof(int);
    int* binscan = (int*)p;           p += (size_t)NB * sizeof(int);
    int* bbase = (int*)p;             p += (size_t)(NB + 1) * sizeof(int);
    int* bcursor = (int*)p;           p += (size_t)NB * sizeof(int);
    int* bblksum = (int*)p;           p += (size_t)(nblkB + 1) * sizeof(int);
    int* bblkoff = (int*)p;           p += (size_t)(nblkB + 1) * sizeof(int);
    size_t needed_tC = (size_t)(p - (char*)d_ws);

    int gemm_blocks = (N + BM - 1) / BM;

    if (ws_size >= needed_tC && N <= 131072) {
        // ---- binned fused path: no node-level CSR at all ----
        prep_wbfs_kernel<<<(D * D + 255) / 256, 256, 0, stream>>>(w, wbfs);
        hipMemsetAsync(bhist, 0, (size_t)NB * sizeof(int), stream);
        x_to_bf16_split_kernel<<<2048, 256, 0, stream>>>(x, xbf, (long long)N * 16);
        bhist_kernel<<<200, 512, 0, stream>>>(ei, bhist, E, NB);
        scan_blocks_kernel<<<nblkB, SCAN_BLK, 0, stream>>>(bhist, binscan, bblksum, NB);
        scan_sums_kernel<<<1, 128, 0, stream>>>(bblksum, bblkoff, nblkB);
        bucket_finalize_kernel<<<(NB + 255) / 256, 256, 0, stream>>>(bhist, binscan, bblkoff,
                                                                     bbase, bcursor, NB, E);
        binA_kernel<<<(E + 8191) / 8192, 512, 0, stream>>>(ei, ev, bcursor, ebin, E, NB);
        gather_bin_kernel<<<NB, 512, 0, stream>>>(bbase, ebin, xbf, aggbf, N);
        linear_mfma_bf_kernel<<<gemm_blocks, 256, 0, stream>>>(aggbf, wbfs, out, N);
    } else if (ws_size >= needed_t2) {
        bool bf16 = (ws_size >= needed_t1);
        prep_wbfs_kernel<<<(D * D + 255) / 256, 256, 0, stream>>>(w, wbfs);
        hipMemsetAsync(deg, 0, (size_t)N * sizeof(int), stream);
        if (bf16)
            x_to_bf16_kernel<<<2048, 256, 0, stream>>>(x, xbf, (long long)N * D / 4);
        hist_rank_kernel<<<(E + 255) / 256, 256, 0, stream>>>(ei, deg, rank, E);
        scan_blocks_kernel<<<nblk, SCAN_BLK, 0, stream>>>(deg, inscan, blksum, N);
        scan_sums_kernel<<<1, 128, 0, stream>>>(blksum, blkoff, nblk);
        finalize_offsets_kernel<<<(N + 255) / 256, 256, 0, stream>>>(deg, inscan, blkoff,
                                                                     off, N, E);
        edge_scatter2_kernel<<<(E + 255) / 256, 256, 0, stream>>>(ei, ev, off, rank, srt, E);
        if (bf16) {
            gather_bf16_kernel<<<(N + 3) / 4, 256, 0, stream>>>(off, srt, xbf, out, N);
        } else {
            // fp32 gather via srt (rare tier): reuse scatter-free gather on fp32 x
            gather_bf16_kernel<<<(N + 3) / 4, 256, 0, stream>>>(off, srt, xbf, out, N);
        }
        linear_mfma_kernel<<<gemm_blocks, 256, 0, stream>>>(out, wbfs, N);
    } else {
        transpose_w_kernel<<<(D * D + 255) / 256, 256, 0, stream>>>(w, wt);
        hipMemsetAsync(d_out, 0, (size_t)out_size * sizeof(float), stream);
        scatter_kernel<<<4096, 256, 0, stream>>>(ei, ev, x, out, E);
        linear_tiled_kernel<<<gemm_blocks, 256, 0, stream>>>(out, wt, N);
    }
}

// Round 9
// 1263.353 us; speedup vs baseline: 1.0008x; 1.0008x over previous
//
#include <hip/hip_runtime.h>

#define D 128
#define SCAN_BLK 1024
#define BM 64
#define KC 32
#define BSH 6            // bucket shift: 64 nodes per bucket
#define BNODES 64

using short8 = __attribute__((ext_vector_type(8))) short;
using floatx4 = __attribute__((ext_vector_type(4))) float;

__device__ __forceinline__ unsigned int f2bf(unsigned int b) {
    return (b + 0x7fffu + ((b >> 16) & 1u)) >> 16;  // RNE fp32->bf16 (as u16)
}

// Native LDS f32 atomic add (fire-and-forget, no CAS loop).  Generic->LDS
// address: low 32 bits of the flat address are the LDS byte offset.
// NOTE deliberately NO "memory" clobber: keeps global loads free to hoist
// across it.  Pair with an explicit s_waitcnt lgkmcnt(0) before the barrier.
__device__ __forceinline__ void lds_add_f32(float* p, float v) {
    unsigned off = (unsigned)(unsigned long long)p;
    asm volatile("ds_add_f32 %0, %1" :: "v"(off), "v"(v));
}

// ---------- W transpose (tier-3 VALU path) ----------
__global__ void transpose_w_kernel(const float* __restrict__ w, float* __restrict__ wt) {
    int t = blockIdx.x * 256 + threadIdx.x;
    if (t < D * D) {
        int o = t >> 7;
        int k = t & 127;
        wt[k * D + o] = w[t];
    }
}

// ---------- W -> bf16, XOR-swizzled [n][k] table for MFMA B-frags ----------
__global__ void prep_wbfs_kernel(const float* __restrict__ w, unsigned short* __restrict__ wbfs) {
    int t = blockIdx.x * 256 + threadIdx.x;
    if (t < D * D) {
        int n = t >> 7, k = t & 127;
        wbfs[n * 128 + (k ^ ((n & 7) << 3))] = (unsigned short)f2bf(__float_as_uint(w[t]));
    }
}

// ---------- x -> bf16 SPLIT packing: xbf[n*64+q] = bf16(x[n][q]) | bf16(x[n][q+64])<<16
__global__ __launch_bounds__(256) void x_to_bf16_split_kernel(const float* __restrict__ x,
                                                              unsigned int* __restrict__ xbf,
                                                              long long ngrp /* N*16 */) {
    long long g = (long long)blockIdx.x * 256 + threadIdx.x;
    long long stride = (long long)gridDim.x * 256;
    for (; g < ngrp; g += stride) {
        long long i = g * 4;
        long long node = i >> 6;
        int q = (int)(i & 63);
        const float* row = x + node * D;
        float4 lo = *(const float4*)&row[q];
        float4 hi = *(const float4*)&row[q + 64];
        uint4 o;
        o.x = f2bf(__float_as_uint(lo.x)) | (f2bf(__float_as_uint(hi.x)) << 16);
        o.y = f2bf(__float_as_uint(lo.y)) | (f2bf(__float_as_uint(hi.y)) << 16);
        o.z = f2bf(__float_as_uint(lo.z)) | (f2bf(__float_as_uint(hi.z)) << 16);
        o.w = f2bf(__float_as_uint(lo.w)) | (f2bf(__float_as_uint(hi.w)) << 16);
        *(uint4*)&xbf[i] = o;
    }
}

// ---------- x -> bf16 PAIR packing (fallback gather path) ----------
__global__ __launch_bounds__(256) void x_to_bf16_kernel(const float* __restrict__ x,
                                                        unsigned int* __restrict__ xbf,
                                                        long long nvec) {
    long long i = (long long)blockIdx.x * 256 + threadIdx.x;
    long long stride = (long long)gridDim.x * 256;
    for (; i < nvec; i += stride) {
        float4 v = ((const float4*)x)[i];
        unsigned int b0 = f2bf(__float_as_uint(v.x)), b1 = f2bf(__float_as_uint(v.y));
        unsigned int b2 = f2bf(__float_as_uint(v.z)), b3 = f2bf(__float_as_uint(v.w));
        ((uint2*)xbf)[i] = make_uint2(b0 | (b1 << 16), b2 | (b3 << 16));
    }
}

// ---------- bucket histogram (64-node buckets) ----------
__global__ __launch_bounds__(512) void bhist_kernel(const int* __restrict__ ei, int* bhist,
                                                    int E, int NB) {
    __shared__ int h[2048];
    int tid = threadIdx.x;
    for (int i = tid; i < NB; i += 512) h[i] = 0;
    __syncthreads();
    for (long long e = (long long)blockIdx.x * 512 + tid; e < E; e += (long long)gridDim.x * 512)
        atomicAdd(&h[((unsigned)ei[e]) >> BSH], 1);
    __syncthreads();
    for (int i = tid; i < NB; i += 512)
        if (h[i]) atomicAdd(&bhist[i], h[i]);
}

// ---------- scans ----------
__global__ __launch_bounds__(SCAN_BLK) void scan_blocks_kernel(const int* __restrict__ deg,
                                                               int* inscan, int* blksum, int n) {
    __shared__ int s[SCAN_BLK];
    int gid = blockIdx.x * SCAN_BLK + threadIdx.x;
    int v = (gid < n) ? deg[gid] : 0;
    s[threadIdx.x] = v;
    __syncthreads();
    for (int d = 1; d < SCAN_BLK; d <<= 1) {
        int t = (threadIdx.x >= d) ? s[threadIdx.x - d] : 0;
        __syncthreads();
        s[threadIdx.x] += t;
        __syncthreads();
    }
    if (gid < n) inscan[gid] = s[threadIdx.x];
    if (threadIdx.x == SCAN_BLK - 1) blksum[blockIdx.x] = s[SCAN_BLK - 1];
}

__global__ __launch_bounds__(128) void scan_sums_kernel(const int* __restrict__ blksum,
                                                        int* blkoff, int nblk) {
    __shared__ int s[128];
    int v = (threadIdx.x < nblk) ? blksum[threadIdx.x] : 0;
    s[threadIdx.x] = v;
    __syncthreads();
    for (int d = 1; d < 128; d <<= 1) {
        int t = (threadIdx.x >= d) ? s[threadIdx.x - d] : 0;
        __syncthreads();
        s[threadIdx.x] += t;
        __syncthreads();
    }
    if (threadIdx.x < nblk) blkoff[threadIdx.x] = s[threadIdx.x] - v;
}

__global__ void bucket_finalize_kernel(const int* __restrict__ bhist,
                                       const int* __restrict__ binscan,
                                       const int* __restrict__ bblkoff,
                                       int* bbase, int* bcursor, int NB, int E) {
    int g = blockIdx.x * 256 + threadIdx.x;
    if (g < NB) {
        int o = bblkoff[g >> 10] + binscan[g] - bhist[g];  // exclusive
        bbase[g] = o;
        bcursor[g] = o;
    }
    if (g == 0) bbase[NB] = E;
}

// ---------- binA: partition edges into 64-node buckets (order-free) ----------
// pack: src (26b) | dst_local (6b) << 26
__global__ __launch_bounds__(512) void binA_kernel(const int* __restrict__ ei,
                                                   const float* __restrict__ ev,
                                                   int* bcursor, int2* __restrict__ ebin,
                                                   int E, int NB) {
    __shared__ int hist[2048];
    __shared__ int base[2048];
    __shared__ int cnt2[2048];
    int tid = threadIdx.x;
    for (int i = tid; i < NB; i += 512) { hist[i] = 0; cnt2[i] = 0; }
    __syncthreads();
    int e0 = blockIdx.x * 8192;
#pragma unroll
    for (int i = 0; i < 16; ++i) {
        int e = e0 + i * 512 + tid;
        if (e < E) atomicAdd(&hist[((unsigned)ei[e]) >> BSH], 1);
    }
    __syncthreads();
    for (int i = tid; i < NB; i += 512)
        if (hist[i]) base[i] = atomicAdd(&bcursor[i], hist[i]);
    __syncthreads();
#pragma unroll
    for (int i = 0; i < 16; ++i) {
        int e = e0 + i * 512 + tid;
        if (e < E) {
            int dst = ei[e];
            int b = ((unsigned)dst) >> BSH;
            int pos = base[b] + atomicAdd(&cnt2[b], 1);
            ebin[pos] = make_int2(ei[E + e] | ((dst & (BNODES - 1)) << 26),
                                  __float_as_int(ev[e]));
        }
    }
}

// ---------- fused bin-gather: LDS out-tile + NATIVE ds_add_f32, flush bf16 ----------
__global__ __launch_bounds__(512) void gather_bin_kernel(const int* __restrict__ bbase,
                                                         const int2* __restrict__ ebin,
                                                         const unsigned int* __restrict__ xbf,
                                                         unsigned int* __restrict__ aggbf,
                                                         int N) {
    __shared__ float tile[BNODES * D];  // 32 KiB, [node_local][ch]
    int b = blockIdx.x;
    int tid = threadIdx.x;
    int lane = tid & 63;
    for (int i = tid; i < BNODES * D / 4; i += 512)
        ((float4*)tile)[i] = make_float4(0.f, 0.f, 0.f, 0.f);
    __syncthreads();

    int start = bbase[b], end = bbase[b + 1];
    int cnt = end - start;
    if (cnt > 0) {
        int wid = tid >> 6;
        int per = (cnt + 7) >> 3;
        int wbeg = start + wid * per;
        int wend = wbeg + per < end ? wbeg + per : end;
        int e = wbeg;
        for (; e + 3 < wend; e += 4) {
            int2 b0 = ebin[e], b1 = ebin[e + 1], b2 = ebin[e + 2], b3 = ebin[e + 3];
            unsigned int u0 = xbf[(size_t)(b0.x & 0x03FFFFFF) * 64 + lane];
            unsigned int u1 = xbf[(size_t)(b1.x & 0x03FFFFFF) * 64 + lane];
            unsigned int u2 = xbf[(size_t)(b2.x & 0x03FFFFFF) * 64 + lane];
            unsigned int u3 = xbf[(size_t)(b3.x & 0x03FFFFFF) * 64 + lane];
            int d0 = ((unsigned)b0.x) >> 26, d1 = ((unsigned)b1.x) >> 26;
            int d2 = ((unsigned)b2.x) >> 26, d3 = ((unsigned)b3.x) >> 26;
            float v0 = __int_as_float(b0.y), v1 = __int_as_float(b1.y);
            float v2 = __int_as_float(b2.y), v3 = __int_as_float(b3.y);
            // lane handles ch `lane` (lo) and `lane+64` (hi): stride-1 words per op
            lds_add_f32(&tile[d0 * D + lane], v0 * __uint_as_float(u0 << 16));
            lds_add_f32(&tile[d0 * D + 64 + lane], v0 * __uint_as_float(u0 & 0xffff0000u));
            lds_add_f32(&tile[d1 * D + lane], v1 * __uint_as_float(u1 << 16));
            lds_add_f32(&tile[d1 * D + 64 + lane], v1 * __uint_as_float(u1 & 0xffff0000u));
            lds_add_f32(&tile[d2 * D + lane], v2 * __uint_as_float(u2 << 16));
            lds_add_f32(&tile[d2 * D + 64 + lane], v2 * __uint_as_float(u2 & 0xffff0000u));
            lds_add_f32(&tile[d3 * D + lane], v3 * __uint_as_float(u3 << 16));
            lds_add_f32(&tile[d3 * D + 64 + lane], v3 * __uint_as_float(u3 & 0xffff0000u));
        }
        for (; e < wend; ++e) {
            int2 eb = ebin[e];
            unsigned int u = xbf[(size_t)(eb.x & 0x03FFFFFF) * 64 + lane];
            int dl = ((unsigned)eb.x) >> 26;
            float v = __int_as_float(eb.y);
            lds_add_f32(&tile[dl * D + lane], v * __uint_as_float(u << 16));
            lds_add_f32(&tile[dl * D + 64 + lane], v * __uint_as_float(u & 0xffff0000u));
        }
    }
    // compiler doesn't track asm DS ops in lgkmcnt: drain explicitly, then barrier
    asm volatile("s_waitcnt lgkmcnt(0)" ::: "memory");
    __syncthreads();

    // flush: pack pairs (2q,2q+1) -> aggbf (k-contiguous for linear_mfma_bf)
    int node0 = b << BSH;
    for (int i = tid; i < BNODES * 64; i += 512) {
        int nl = i >> 6, q = i & 63;
        int node = node0 + nl;
        if (node < N) {
            float lo = tile[nl * D + 2 * q];
            float hi = tile[nl * D + 2 * q + 1];
            aggbf[(size_t)node * 64 + q] =
                f2bf(__float_as_uint(lo)) | (f2bf(__float_as_uint(hi)) << 16);
        }
    }
}

// ---------- fallback CSR machinery ----------
__global__ void hist_rank_kernel(const int* __restrict__ ei, int* deg,
                                 unsigned short* __restrict__ rank, int E) {
    int e = blockIdx.x * 256 + threadIdx.x;
    if (e < E) rank[e] = (unsigned short)atomicAdd(&deg[ei[e]], 1);
}

__global__ void finalize_offsets_kernel(const int* __restrict__ deg,
                                        const int* __restrict__ inscan,
                                        const int* __restrict__ blkoff,
                                        int* off, int n, int E) {
    int gid = blockIdx.x * 256 + threadIdx.x;
    if (gid < n) off[gid] = blkoff[gid >> 10] + inscan[gid] - deg[gid];
    if (gid == 0) off[n] = E;
}

__global__ void edge_scatter2_kernel(const int* __restrict__ ei, const float* __restrict__ ev,
                                     const int* __restrict__ off,
                                     const unsigned short* __restrict__ rank,
                                     int2* __restrict__ srt, int E) {
    int e = blockIdx.x * 256 + threadIdx.x;
    if (e < E) {
        int dst = ei[e];
        int pos = off[dst] + (int)rank[e];
        srt[pos] = make_int2(ei[E + e], __float_as_int(ev[e]));
    }
}

// fallback gather (PAIR-packed xbf), writes fp32 out
__global__ __launch_bounds__(256) void gather_bf16_kernel(const int* __restrict__ off,
                                                          const int2* __restrict__ srt,
                                                          const unsigned int* __restrict__ xbf,
                                                          float* __restrict__ out, int N) {
    int lane = threadIdx.x & 63;
    int wid = blockIdx.x * 4 + (threadIdx.x >> 6);
    if (wid >= N) return;
    int beg = off[wid], end = off[wid + 1];
    float2 acc = make_float2(0.f, 0.f);
    int e = beg;
    for (; e + 3 < end; e += 4) {
        int2 s0 = srt[e], s1 = srt[e + 1], s2 = srt[e + 2], s3 = srt[e + 3];
        unsigned int u0 = xbf[(size_t)s0.x * 64 + lane];
        unsigned int u1 = xbf[(size_t)s1.x * 64 + lane];
        unsigned int u2 = xbf[(size_t)s2.x * 64 + lane];
        unsigned int u3 = xbf[(size_t)s3.x * 64 + lane];
        float v0 = __int_as_float(s0.y), v1 = __int_as_float(s1.y);
        float v2 = __int_as_float(s2.y), v3 = __int_as_float(s3.y);
        acc.x = fmaf(v0, __uint_as_float(u0 << 16), acc.x);
        acc.y = fmaf(v0, __uint_as_float(u0 & 0xffff0000u), acc.y);
        acc.x = fmaf(v1, __uint_as_float(u1 << 16), acc.x);
        acc.y = fmaf(v1, __uint_as_float(u1 & 0xffff0000u), acc.y);
        acc.x = fmaf(v2, __uint_as_float(u2 << 16), acc.x);
        acc.y = fmaf(v2, __uint_as_float(u2 & 0xffff0000u), acc.y);
        acc.x = fmaf(v3, __uint_as_float(u3 << 16), acc.x);
        acc.y = fmaf(v3, __uint_as_float(u3 & 0xffff0000u), acc.y);
    }
    for (; e < end; ++e) {
        int2 sv = srt[e];
        unsigned int u = xbf[(size_t)sv.x * 64 + lane];
        float v = __int_as_float(sv.y);
        acc.x = fmaf(v, __uint_as_float(u << 16), acc.x);
        acc.y = fmaf(v, __uint_as_float(u & 0xffff0000u), acc.y);
    }
    *(float2*)&out[(size_t)wid * D + lane * 2] = acc;
}

// ---------- MFMA linear, A from packed-bf16 agg -> writes d_out ----------
__global__ __launch_bounds__(256) void linear_mfma_bf_kernel(const unsigned int* __restrict__ aggbf,
                                                             const unsigned short* __restrict__ wbfs,
                                                             float* __restrict__ out, int N) {
    __shared__ __align__(16) unsigned short sW[D * D];
    __shared__ __align__(16) unsigned short sA[BM * D];
    int t = threadIdx.x;
    int row0 = blockIdx.x * BM;
    {
        const uint4* src = (const uint4*)wbfs;
        uint4* dst = (uint4*)sW;
#pragma unroll
        for (int i = 0; i < 8; ++i) dst[i * 256 + t] = src[i * 256 + t];
    }
#pragma unroll
    for (int it = 0; it < 4; ++it) {
        int iv = it * 256 + t;
        int m = iv >> 4;
        int q = iv & 15;
        int r = row0 + m;
        int rcl = r < N ? r : N - 1;
        uint4 v = *(const uint4*)&aggbf[(size_t)rcl * 64 + q * 4];
        *(uint4*)((char*)sA + m * 256 + ((q * 16) ^ ((m & 7) << 4))) = v;
    }
    __syncthreads();

    int lane = t & 63;
    int w = t >> 6;
    int lm = 16 * w + (lane & 15);
    int ln = lane & 15;
    int kg = lane >> 4;

    floatx4 acc[8];
#pragma unroll
    for (int nt = 0; nt < 8; ++nt) acc[nt] = (floatx4){0.f, 0.f, 0.f, 0.f};

#pragma unroll
    for (int ks = 0; ks < 4; ++ks) {
        int kbyte = ks * 64 + kg * 16;
        short8 a = *(const short8*)((const char*)sA + lm * 256 + (kbyte ^ ((lm & 7) << 4)));
#pragma unroll
        for (int nt = 0; nt < 8; ++nt) {
            int n = nt * 16 + ln;
            short8 bfr = *(const short8*)((const char*)sW + n * 256 + (kbyte ^ ((n & 7) << 4)));
            acc[nt] = __builtin_amdgcn_mfma_f32_16x16x32_bf16(a, bfr, acc[nt], 0, 0, 0);
        }
    }

    int rbase = row0 + 16 * w + 4 * kg;
#pragma unroll
    for (int nt = 0; nt < 8; ++nt) {
#pragma unroll
        for (int r = 0; r < 4; ++r) {
            int row = rbase + r;
            if (row < N) out[(size_t)row * D + nt * 16 + ln] = acc[nt][r];
        }
    }
}

// ---------- MFMA linear in-place from fp32 io (fallback) ----------
__global__ __launch_bounds__(256) void linear_mfma_kernel(float* io,
                                                          const unsigned short* __restrict__ wbfs,
                                                          int N) {
    __shared__ __align__(16) unsigned short sW[D * D];
    __shared__ __align__(16) unsigned short sA[BM * D];
    int t = threadIdx.x;
    int row0 = blockIdx.x * BM;
    {
        const uint4* src = (const uint4*)wbfs;
        uint4* dst = (uint4*)sW;
#pragma unroll
        for (int i = 0; i < 8; ++i) dst[i * 256 + t] = src[i * 256 + t];
    }
#pragma unroll
    for (int it = 0; it < 8; ++it) {
        int idx = it * 1024 + t * 4;
        int m = idx >> 7;
        int k0 = idx & 127;
        int r = row0 + m;
        int rcl = r < N ? r : N - 1;
        float4 v = *(const float4*)&io[(size_t)rcl * D + k0];
        unsigned int b0 = f2bf(__float_as_uint(v.x)), b1 = f2bf(__float_as_uint(v.y));
        unsigned int b2 = f2bf(__float_as_uint(v.z)), b3 = f2bf(__float_as_uint(v.w));
        int byteoff = m * 256 + ((k0 * 2) ^ ((m & 7) << 4));
        *(uint2*)((char*)sA + byteoff) = make_uint2(b0 | (b1 << 16), b2 | (b3 << 16));
    }
    __syncthreads();

    int lane = t & 63;
    int w = t >> 6;
    int lm = 16 * w + (lane & 15);
    int ln = lane & 15;
    int kg = lane >> 4;

    floatx4 acc[8];
#pragma unroll
    for (int nt = 0; nt < 8; ++nt) acc[nt] = (floatx4){0.f, 0.f, 0.f, 0.f};

#pragma unroll
    for (int ks = 0; ks < 4; ++ks) {
        int kbyte = ks * 64 + kg * 16;
        short8 a = *(const short8*)((const char*)sA + lm * 256 + (kbyte ^ ((lm & 7) << 4)));
#pragma unroll
        for (int nt = 0; nt < 8; ++nt) {
            int n = nt * 16 + ln;
            short8 bfr = *(const short8*)((const char*)sW + n * 256 + (kbyte ^ ((n & 7) << 4)));
            acc[nt] = __builtin_amdgcn_mfma_f32_16x16x32_bf16(a, bfr, acc[nt], 0, 0, 0);
        }
    }

    int rbase = row0 + 16 * w + 4 * kg;
#pragma unroll
    for (int nt = 0; nt < 8; ++nt) {
#pragma unroll
        for (int r = 0; r < 4; ++r) {
            int row = rbase + r;
            if (row < N) io[(size_t)row * D + nt * 16 + ln] = acc[nt][r];
        }
    }
}

// ---------- tier-3 fallbacks ----------
__global__ __launch_bounds__(256) void scatter_kernel(const int* __restrict__ ei,
                                                      const float* __restrict__ ev,
                                                      const float* __restrict__ x,
                                                      float* agg, int E) {
    int lane = threadIdx.x & 63;
    long long wid = (long long)blockIdx.x * 4 + (threadIdx.x >> 6);
    long long nw = (long long)gridDim.x * 4;
    for (long long e = wid; e < E; e += nw) {
        int i = ei[e];
        int j = ei[(long long)E + e];
        float v = ev[e];
        float2 xv = *(const float2*)&x[(size_t)j * D + lane * 2];
        float* op = &agg[(size_t)i * D + lane * 2];
        unsafeAtomicAdd(&op[0], v * xv.x);
        unsafeAtomicAdd(&op[1], v * xv.y);
    }
}

__global__ __launch_bounds__(256) void linear_tiled_kernel(float* io,
                                                           const float* __restrict__ wt,
                                                           int N) {
    __shared__ float sA[KC][BM + 4];
    __shared__ float sW2[KC][D];
    int t = threadIdx.x;
    int tc = t & 15;
    int tr = t >> 4;
    int row0 = blockIdx.x * BM;

    float acc[4][8];
#pragma unroll
    for (int i = 0; i < 4; ++i)
#pragma unroll
        for (int j = 0; j < 8; ++j) acc[i][j] = 0.f;

    int ldA_r = t >> 3;
    int ldA_k = (t & 7) * 4;
    int ldW_k = t >> 5;
    int ldW_c = (t & 31) * 4;

    for (int kc = 0; kc < D; kc += KC) {
#pragma unroll
        for (int rr = 0; rr < BM; rr += 32) {
            int r = row0 + ldA_r + rr;
            int rcl = r < N ? r : N - 1;
            float4 v = *(const float4*)&io[(size_t)rcl * D + kc + ldA_k];
            sA[ldA_k + 0][ldA_r + rr] = v.x;
            sA[ldA_k + 1][ldA_r + rr] = v.y;
            sA[ldA_k + 2][ldA_r + rr] = v.z;
            sA[ldA_k + 3][ldA_r + rr] = v.w;
        }
#pragma unroll
        for (int kk = 0; kk < KC; kk += 8)
            *(float4*)&sW2[ldW_k + kk][ldW_c] =
                *(const float4*)&wt[(size_t)(kc + ldW_k + kk) * D + ldW_c];
        __syncthreads();

#pragma unroll 8
        for (int k = 0; k < KC; ++k) {
            float4 a = *(const float4*)&sA[k][tr * 4];
            float4 w0 = *(const float4*)&sW2[k][tc * 8];
            float4 w1 = *(const float4*)&sW2[k][tc * 8 + 4];
            float av[4] = {a.x, a.y, a.z, a.w};
            float wv[8] = {w0.x, w0.y, w0.z, w0.w, w1.x, w1.y, w1.z, w1.w};
#pragma unroll
            for (int i = 0; i < 4; ++i)
#pragma unroll
                for (int j = 0; j < 8; ++j)
                    acc[i][j] = fmaf(av[i], wv[j], acc[i][j]);
        }
        __syncthreads();
    }

#pragma unroll
    for (int i = 0; i < 4; ++i) {
        int r = row0 + tr * 4 + i;
        if (r < N) {
            *(float4*)&io[(size_t)r * D + tc * 8] = *(float4*)&acc[i][0];
            *(float4*)&io[(size_t)r * D + tc * 8 + 4] = *(float4*)&acc[i][4];
        }
    }
}

extern "C" void kernel_launch(void* const* d_in, const int* in_sizes, int n_in,
                              void* d_out, int out_size, void* d_ws, size_t ws_size,
                              hipStream_t stream) {
    const float* x = (const float*)d_in[0];
    const float* w = (const float*)d_in[1];
    const int* ei = (const int*)d_in[2];   // [2,E] int32 (dst row, then src row)
    const float* ev = (const float*)d_in[3];

    int N = in_sizes[0] / D;
    int E = in_sizes[3];
    int nblk = (N + SCAN_BLK - 1) / SCAN_BLK;
    int NB = (N + BNODES - 1) >> BSH;          // 64-node buckets
    int nblkB = (NB + SCAN_BLK - 1) / SCAN_BLK;

    float* out = (float*)d_out;

    // workspace layout
    char* p = (char*)d_ws;
    float* wt = (float*)p;            p += (size_t)D * D * sizeof(float);
    unsigned short* wbfs = (unsigned short*)p;  p += (size_t)D * D * sizeof(unsigned short);
    int* deg = (int*)p;               p += (size_t)N * sizeof(int);
    int* inscan = (int*)p;            p += (size_t)N * sizeof(int);
    int* off = (int*)p;               p += (size_t)(N + 1) * sizeof(int);
    int* blksum = (int*)p;            p += (size_t)nblk * sizeof(int);
    int* blkoff = (int*)p;            p += (size_t)nblk * sizeof(int);
    p = (char*)(((uintptr_t)p + 255) & ~(uintptr_t)255);
    unsigned short* rank = (unsigned short*)p;  p += (size_t)E * sizeof(unsigned short);
    p = (char*)(((uintptr_t)p + 255) & ~(uintptr_t)255);
    int2* srt = (int2*)p;             p += (size_t)E * sizeof(int2);
    size_t needed_t2 = (size_t)(p - (char*)d_ws);
    p = (char*)(((uintptr_t)p + 255) & ~(uintptr_t)255);
    unsigned int* xbf = (unsigned int*)p;  p += (size_t)N * (D / 2) * sizeof(unsigned int);
    size_t needed_t1 = (size_t)(p - (char*)d_ws);
    p = (char*)(((uintptr_t)p + 255) & ~(uintptr_t)255);
    int2* ebin = (int2*)p;            p += (size_t)E * sizeof(int2);
    p = (char*)(((uintptr_t)p + 255) & ~(uintptr_t)255);
    unsigned int* aggbf = (unsigned int*)p;  p += (size_t)N * (D / 2) * sizeof(unsigned int);
    int* bhist = (int*)p;             p += (size_t)NB * sizeof(int);
    int* binscan = (int*)p;           p += (size_t)NB * sizeof(int);
    int* bbase = (int*)p;             p += (size_t)(NB + 1) * sizeof(int);
    int* bcursor = (int*)p;           p += (size_t)NB * sizeof(int);
    int* bblksum = (int*)p;           p += (size_t)(nblkB + 1) * sizeof(int);
    int* bblkoff = (int*)p;           p += (size_t)(nblkB + 1) * sizeof(int);
    size_t needed_tC = (size_t)(p - (char*)d_ws);

    int gemm_blocks = (N + BM - 1) / BM;

    if (ws_size >= needed_tC && N <= 131072) {
        // ---- binned fused path: no node-level CSR at all ----
        prep_wbfs_kernel<<<(D * D + 255) / 256, 256, 0, stream>>>(w, wbfs);
        hipMemsetAsync(bhist, 0, (size_t)NB * sizeof(int), stream);
        x_to_bf16_split_kernel<<<2048, 256, 0, stream>>>(x, xbf, (long long)N * 16);
        bhist_kernel<<<200, 512, 0, stream>>>(ei, bhist, E, NB);
        scan_blocks_kernel<<<nblkB, SCAN_BLK, 0, stream>>>(bhist, binscan, bblksum, NB);
        scan_sums_kernel<<<1, 128, 0, stream>>>(bblksum, bblkoff, nblkB);
        bucket_finalize_kernel<<<(NB + 255) / 256, 256, 0, stream>>>(bhist, binscan, bblkoff,
                                                                     bbase, bcursor, NB, E);
        binA_kernel<<<(E + 8191) / 8192, 512, 0, stream>>>(ei, ev, bcursor, ebin, E, NB);
        gather_bin_kernel<<<NB, 512, 0, stream>>>(bbase, ebin, xbf, aggbf, N);
        linear_mfma_bf_kernel<<<gemm_blocks, 256, 0, stream>>>(aggbf, wbfs, out, N);
    } else if (ws_size >= needed_t2) {
        prep_wbfs_kernel<<<(D * D + 255) / 256, 256, 0, stream>>>(w, wbfs);
        hipMemsetAsync(deg, 0, (size_t)N * sizeof(int), stream);
        x_to_bf16_kernel<<<2048, 256, 0, stream>>>(x, xbf, (long long)N * D / 4);
        hist_rank_kernel<<<(E + 255) / 256, 256, 0, stream>>>(ei, deg, rank, E);
        scan_blocks_kernel<<<nblk, SCAN_BLK, 0, stream>>>(deg, inscan, blksum, N);
        scan_sums_kernel<<<1, 128, 0, stream>>>(blksum, blkoff, nblk);
        finalize_offsets_kernel<<<(N + 255) / 256, 256, 0, stream>>>(deg, inscan, blkoff,
                                                                     off, N, E);
        edge_scatter2_kernel<<<(E + 255) / 256, 256, 0, stream>>>(ei, ev, off, rank, srt, E);
        gather_bf16_kernel<<<(N + 3) / 4, 256, 0, stream>>>(off, srt, xbf, out, N);
        linear_mfma_kernel<<<gemm_blocks, 256, 0, stream>>>(out, wbfs, N);
    } else {
        transpose_w_kernel<<<(D * D + 255) / 256, 256, 0, stream>>>(w, wt);
        hipMemsetAsync(d_out, 0, (size_t)out_size * sizeof(float), stream);
        scatter_kernel<<<4096, 256, 0, stream>>>(ei, ev, x, out, E);
        linear_tiled_kernel<<<gemm_blocks, 256, 0, stream>>>(out, wt, N);
    }
}

// Round 10
// 208.936 us; speedup vs baseline: 6.0517x; 6.0466x over previous
//
#include <hip/hip_runtime.h>

#define D 128
#define SCAN_BLK 1024
#define BM 64
#define KC 32

using short8 = __attribute__((ext_vector_type(8))) short;
using floatx4 = __attribute__((ext_vector_type(4))) float;

__device__ __forceinline__ unsigned int f2bf(unsigned int b) {
    return (b + 0x7fffu + ((b >> 16) & 1u)) >> 16;  // RNE fp32->bf16 (as u16)
}

// ---------- W transpose (tier-3 VALU path) ----------
__global__ void transpose_w_kernel(const float* __restrict__ w, float* __restrict__ wt) {
    int t = blockIdx.x * 256 + threadIdx.x;
    if (t < D * D) {
        int o = t >> 7;
        int k = t & 127;
        wt[k * D + o] = w[t];
    }
}

// ---------- W -> bf16, XOR-swizzled [n][k] table for MFMA B-frags ----------
__global__ void prep_wbfs_kernel(const float* __restrict__ w, unsigned short* __restrict__ wbfs) {
    int t = blockIdx.x * 256 + threadIdx.x;
    if (t < D * D) {
        int n = t >> 7, k = t & 127;
        wbfs[n * 128 + (k ^ ((n & 7) << 3))] = (unsigned short)f2bf(__float_as_uint(w[t]));
    }
}

// ---------- x -> bf16 PAIR packing: xbf[n*64+q] = bf16(x[n][2q]) | bf16(x[n][2q+1])<<16
__global__ __launch_bounds__(256) void x_to_bf16_kernel(const float* __restrict__ x,
                                                        unsigned int* __restrict__ xbf,
                                                        long long nvec) {
    long long i = (long long)blockIdx.x * 256 + threadIdx.x;
    long long stride = (long long)gridDim.x * 256;
    for (; i < nvec; i += stride) {
        float4 v = ((const float4*)x)[i];
        unsigned int b0 = f2bf(__float_as_uint(v.x)), b1 = f2bf(__float_as_uint(v.y));
        unsigned int b2 = f2bf(__float_as_uint(v.z)), b3 = f2bf(__float_as_uint(v.w));
        ((uint2*)xbf)[i] = make_uint2(b0 | (b1 << 16), b2 | (b3 << 16));
    }
}

// ---------- hist + rank: rank[e] = arrival order within dst segment ----------
__global__ void hist_rank_kernel(const int* __restrict__ ei, int* deg,
                                 unsigned short* __restrict__ rank, int E) {
    int e = blockIdx.x * 256 + threadIdx.x;
    if (e < E) rank[e] = (unsigned short)atomicAdd(&deg[ei[e]], 1);
}

// ---------- scans ----------
__global__ __launch_bounds__(SCAN_BLK) void scan_blocks_kernel(const int* __restrict__ deg,
                                                               int* inscan, int* blksum, int n) {
    __shared__ int s[SCAN_BLK];
    int gid = blockIdx.x * SCAN_BLK + threadIdx.x;
    int v = (gid < n) ? deg[gid] : 0;
    s[threadIdx.x] = v;
    __syncthreads();
    for (int d = 1; d < SCAN_BLK; d <<= 1) {
        int t = (threadIdx.x >= d) ? s[threadIdx.x - d] : 0;
        __syncthreads();
        s[threadIdx.x] += t;
        __syncthreads();
    }
    if (gid < n) inscan[gid] = s[threadIdx.x];
    if (threadIdx.x == SCAN_BLK - 1) blksum[blockIdx.x] = s[SCAN_BLK - 1];
}

__global__ __launch_bounds__(128) void scan_sums_kernel(const int* __restrict__ blksum,
                                                        int* blkoff, int nblk) {
    __shared__ int s[128];
    int v = (threadIdx.x < nblk) ? blksum[threadIdx.x] : 0;
    s[threadIdx.x] = v;
    __syncthreads();
    for (int d = 1; d < 128; d <<= 1) {
        int t = (threadIdx.x >= d) ? s[threadIdx.x - d] : 0;
        __syncthreads();
        s[threadIdx.x] += t;
        __syncthreads();
    }
    if (threadIdx.x < nblk) blkoff[threadIdx.x] = s[threadIdx.x] - v;
}

__global__ void finalize_offsets_kernel(const int* __restrict__ deg,
                                        const int* __restrict__ inscan,
                                        const int* __restrict__ blkoff,
                                        int* off, int n, int E) {
    int gid = blockIdx.x * 256 + threadIdx.x;
    if (gid < n) off[gid] = blkoff[gid >> 10] + inscan[gid] - deg[gid];  // exclusive
    if (gid == 0) off[n] = E;
}

// ---------- reorder edges, no atomics: pos = off[dst] + rank[e] ----------
__global__ void edge_scatter2_kernel(const int* __restrict__ ei, const float* __restrict__ ev,
                                     const int* __restrict__ off,
                                     const unsigned short* __restrict__ rank,
                                     int2* __restrict__ srt, int E) {
    int e = blockIdx.x * 256 + threadIdx.x;
    if (e < E) {
        int dst = ei[e];
        int pos = off[dst] + (int)rank[e];
        srt[pos] = make_int2(ei[E + e], __float_as_int(ev[e]));
    }
}

// ---------- CSR gather from bf16 table; AGGBF: emit packed-bf16 agg ----------
template <bool AGGBF>
__global__ __launch_bounds__(256) void gather_bf16_kernel(const int* __restrict__ off,
                                                          const int2* __restrict__ srt,
                                                          const unsigned int* __restrict__ xbf,
                                                          float* __restrict__ out,
                                                          unsigned int* __restrict__ aggbf,
                                                          int N) {
    int lane = threadIdx.x & 63;
    int wid = blockIdx.x * 4 + (threadIdx.x >> 6);
    if (wid >= N) return;
    int beg = off[wid], end = off[wid + 1];
    float2 acc = make_float2(0.f, 0.f);
    int e = beg;
    for (; e + 3 < end; e += 4) {
        int2 s0 = srt[e], s1 = srt[e + 1], s2 = srt[e + 2], s3 = srt[e + 3];
        unsigned int u0 = xbf[(size_t)s0.x * 64 + lane];
        unsigned int u1 = xbf[(size_t)s1.x * 64 + lane];
        unsigned int u2 = xbf[(size_t)s2.x * 64 + lane];
        unsigned int u3 = xbf[(size_t)s3.x * 64 + lane];
        float v0 = __int_as_float(s0.y), v1 = __int_as_float(s1.y);
        float v2 = __int_as_float(s2.y), v3 = __int_as_float(s3.y);
        acc.x = fmaf(v0, __uint_as_float(u0 << 16), acc.x);
        acc.y = fmaf(v0, __uint_as_float(u0 & 0xffff0000u), acc.y);
        acc.x = fmaf(v1, __uint_as_float(u1 << 16), acc.x);
        acc.y = fmaf(v1, __uint_as_float(u1 & 0xffff0000u), acc.y);
        acc.x = fmaf(v2, __uint_as_float(u2 << 16), acc.x);
        acc.y = fmaf(v2, __uint_as_float(u2 & 0xffff0000u), acc.y);
        acc.x = fmaf(v3, __uint_as_float(u3 << 16), acc.x);
        acc.y = fmaf(v3, __uint_as_float(u3 & 0xffff0000u), acc.y);
    }
    for (; e < end; ++e) {
        int2 sv = srt[e];
        unsigned int u = xbf[(size_t)sv.x * 64 + lane];
        float v = __int_as_float(sv.y);
        acc.x = fmaf(v, __uint_as_float(u << 16), acc.x);
        acc.y = fmaf(v, __uint_as_float(u & 0xffff0000u), acc.y);
    }
    if (AGGBF) {
        // lane owns channels {2*lane, 2*lane+1} -> k-contiguous packed row
        unsigned int pk = f2bf(__float_as_uint(acc.x)) | (f2bf(__float_as_uint(acc.y)) << 16);
        aggbf[(size_t)wid * 64 + lane] = pk;
    } else {
        *(float2*)&out[(size_t)wid * D + lane * 2] = acc;
    }
}

// ---------- MFMA linear, A from packed-bf16 agg -> writes d_out ----------
__global__ __launch_bounds__(256) void linear_mfma_bf_kernel(const unsigned int* __restrict__ aggbf,
                                                             const unsigned short* __restrict__ wbfs,
                                                             float* __restrict__ out, int N) {
    __shared__ __align__(16) unsigned short sW[D * D];   // 32 KiB, swizzled [n][k]
    __shared__ __align__(16) unsigned short sA[BM * D];  // 16 KiB, swizzled [m][k]
    int t = threadIdx.x;
    int row0 = blockIdx.x * BM;
    {
        const uint4* src = (const uint4*)wbfs;
        uint4* dst = (uint4*)sW;
#pragma unroll
        for (int i = 0; i < 8; ++i) dst[i * 256 + t] = src[i * 256 + t];
    }
#pragma unroll
    for (int it = 0; it < 4; ++it) {
        int iv = it * 256 + t;  // uint4 id 0..1023
        int m = iv >> 4;        // row in tile
        int q = iv & 15;        // 16B chunk within row
        int r = row0 + m;
        int rcl = r < N ? r : N - 1;
        uint4 v = *(const uint4*)&aggbf[(size_t)rcl * 64 + q * 4];
        *(uint4*)((char*)sA + m * 256 + ((q * 16) ^ ((m & 7) << 4))) = v;
    }
    __syncthreads();

    int lane = t & 63;
    int w = t >> 6;
    int lm = 16 * w + (lane & 15);
    int ln = lane & 15;
    int kg = lane >> 4;

    floatx4 acc[8];
#pragma unroll
    for (int nt = 0; nt < 8; ++nt) acc[nt] = (floatx4){0.f, 0.f, 0.f, 0.f};

#pragma unroll
    for (int ks = 0; ks < 4; ++ks) {
        int kbyte = ks * 64 + kg * 16;
        short8 a = *(const short8*)((const char*)sA + lm * 256 + (kbyte ^ ((lm & 7) << 4)));
#pragma unroll
        for (int nt = 0; nt < 8; ++nt) {
            int n = nt * 16 + ln;
            short8 bfr = *(const short8*)((const char*)sW + n * 256 + (kbyte ^ ((n & 7) << 4)));
            acc[nt] = __builtin_amdgcn_mfma_f32_16x16x32_bf16(a, bfr, acc[nt], 0, 0, 0);
        }
    }

    int rbase = row0 + 16 * w + 4 * kg;
#pragma unroll
    for (int nt = 0; nt < 8; ++nt) {
#pragma unroll
        for (int r = 0; r < 4; ++r) {
            int row = rbase + r;
            if (row < N) out[(size_t)row * D + nt * 16 + ln] = acc[nt][r];
        }
    }
}

// ---------- MFMA linear in-place from fp32 io (tier-2 fallback) ----------
__global__ __launch_bounds__(256) void linear_mfma_kernel(float* io,
                                                          const unsigned short* __restrict__ wbfs,
                                                          int N) {
    __shared__ __align__(16) unsigned short sW[D * D];
    __shared__ __align__(16) unsigned short sA[BM * D];
    int t = threadIdx.x;
    int row0 = blockIdx.x * BM;
    {
        const uint4* src = (const uint4*)wbfs;
        uint4* dst = (uint4*)sW;
#pragma unroll
        for (int i = 0; i < 8; ++i) dst[i * 256 + t] = src[i * 256 + t];
    }
#pragma unroll
    for (int it = 0; it < 8; ++it) {
        int idx = it * 1024 + t * 4;
        int m = idx >> 7;
        int k0 = idx & 127;
        int r = row0 + m;
        int rcl = r < N ? r : N - 1;
        float4 v = *(const float4*)&io[(size_t)rcl * D + k0];
        unsigned int b0 = f2bf(__float_as_uint(v.x)), b1 = f2bf(__float_as_uint(v.y));
        unsigned int b2 = f2bf(__float_as_uint(v.z)), b3 = f2bf(__float_as_uint(v.w));
        int byteoff = m * 256 + ((k0 * 2) ^ ((m & 7) << 4));
        *(uint2*)((char*)sA + byteoff) = make_uint2(b0 | (b1 << 16), b2 | (b3 << 16));
    }
    __syncthreads();

    int lane = t & 63;
    int w = t >> 6;
    int lm = 16 * w + (lane & 15);
    int ln = lane & 15;
    int kg = lane >> 4;

    floatx4 acc[8];
#pragma unroll
    for (int nt = 0; nt < 8; ++nt) acc[nt] = (floatx4){0.f, 0.f, 0.f, 0.f};

#pragma unroll
    for (int ks = 0; ks < 4; ++ks) {
        int kbyte = ks * 64 + kg * 16;
        short8 a = *(const short8*)((const char*)sA + lm * 256 + (kbyte ^ ((lm & 7) << 4)));
#pragma unroll
        for (int nt = 0; nt < 8; ++nt) {
            int n = nt * 16 + ln;
            short8 bfr = *(const short8*)((const char*)sW + n * 256 + (kbyte ^ ((n & 7) << 4)));
            acc[nt] = __builtin_amdgcn_mfma_f32_16x16x32_bf16(a, bfr, acc[nt], 0, 0, 0);
        }
    }

    int rbase = row0 + 16 * w + 4 * kg;
#pragma unroll
    for (int nt = 0; nt < 8; ++nt) {
#pragma unroll
        for (int r = 0; r < 4; ++r) {
            int row = rbase + r;
            if (row < N) io[(size_t)row * D + nt * 16 + ln] = acc[nt][r];
        }
    }
}

// ---------- tier-3 fallbacks ----------
__global__ __launch_bounds__(256) void scatter_kernel(const int* __restrict__ ei,
                                                      const float* __restrict__ ev,
                                                      const float* __restrict__ x,
                                                      float* agg, int E) {
    int lane = threadIdx.x & 63;
    long long wid = (long long)blockIdx.x * 4 + (threadIdx.x >> 6);
    long long nw = (long long)gridDim.x * 4;
    for (long long e = wid; e < E; e += nw) {
        int i = ei[e];
        int j = ei[(long long)E + e];
        float v = ev[e];
        float2 xv = *(const float2*)&x[(size_t)j * D + lane * 2];
        float* op = &agg[(size_t)i * D + lane * 2];
        unsafeAtomicAdd(&op[0], v * xv.x);
        unsafeAtomicAdd(&op[1], v * xv.y);
    }
}

__global__ __launch_bounds__(256) void linear_tiled_kernel(float* io,
                                                           const float* __restrict__ wt,
                                                           int N) {
    __shared__ float sA[KC][BM + 4];
    __shared__ float sW2[KC][D];
    int t = threadIdx.x;
    int tc = t & 15;
    int tr = t >> 4;
    int row0 = blockIdx.x * BM;

    float acc[4][8];
#pragma unroll
    for (int i = 0; i < 4; ++i)
#pragma unroll
        for (int j = 0; j < 8; ++j) acc[i][j] = 0.f;

    int ldA_r = t >> 3;
    int ldA_k = (t & 7) * 4;
    int ldW_k = t >> 5;
    int ldW_c = (t & 31) * 4;

    for (int kc = 0; kc < D; kc += KC) {
#pragma unroll
        for (int rr = 0; rr < BM; rr += 32) {
            int r = row0 + ldA_r + rr;
            int rcl = r < N ? r : N - 1;
            float4 v = *(const float4*)&io[(size_t)rcl * D + kc + ldA_k];
            sA[ldA_k + 0][ldA_r + rr] = v.x;
            sA[ldA_k + 1][ldA_r + rr] = v.y;
            sA[ldA_k + 2][ldA_r + rr] = v.z;
            sA[ldA_k + 3][ldA_r + rr] = v.w;
        }
#pragma unroll
        for (int kk = 0; kk < KC; kk += 8)
            *(float4*)&sW2[ldW_k + kk][ldW_c] =
                *(const float4*)&wt[(size_t)(kc + ldW_k + kk) * D + ldW_c];
        __syncthreads();

#pragma unroll 8
        for (int k = 0; k < KC; ++k) {
            float4 a = *(const float4*)&sA[k][tr * 4];
            float4 w0 = *(const float4*)&sW2[k][tc * 8];
            float4 w1 = *(const float4*)&sW2[k][tc * 8 + 4];
            float av[4] = {a.x, a.y, a.z, a.w};
            float wv[8] = {w0.x, w0.y, w0.z, w0.w, w1.x, w1.y, w1.z, w1.w};
#pragma unroll
            for (int i = 0; i < 4; ++i)
#pragma unroll
                for (int j = 0; j < 8; ++j)
                    acc[i][j] = fmaf(av[i], wv[j], acc[i][j]);
        }
        __syncthreads();
    }

#pragma unroll
    for (int i = 0; i < 4; ++i) {
        int r = row0 + tr * 4 + i;
        if (r < N) {
            *(float4*)&io[(size_t)r * D + tc * 8] = *(float4*)&acc[i][0];
            *(float4*)&io[(size_t)r * D + tc * 8 + 4] = *(float4*)&acc[i][4];
        }
    }
}

extern "C" void kernel_launch(void* const* d_in, const int* in_sizes, int n_in,
                              void* d_out, int out_size, void* d_ws, size_t ws_size,
                              hipStream_t stream) {
    const float* x = (const float*)d_in[0];
    const float* w = (const float*)d_in[1];
    const int* ei = (const int*)d_in[2];   // [2,E] int32 (dst row, then src row)
    const float* ev = (const float*)d_in[3];

    int N = in_sizes[0] / D;
    int E = in_sizes[3];
    int nblk = (N + SCAN_BLK - 1) / SCAN_BLK;

    float* out = (float*)d_out;

    // workspace layout (progressive tiers)
    char* p = (char*)d_ws;
    float* wt = (float*)p;            p += (size_t)D * D * sizeof(float);
    unsigned short* wbfs = (unsigned short*)p;  p += (size_t)D * D * sizeof(unsigned short);
    int* deg = (int*)p;               p += (size_t)N * sizeof(int);
    int* inscan = (int*)p;            p += (size_t)N * sizeof(int);
    int* off = (int*)p;               p += (size_t)(N + 1) * sizeof(int);
    int* blksum = (int*)p;            p += (size_t)nblk * sizeof(int);
    int* blkoff = (int*)p;            p += (size_t)nblk * sizeof(int);
    p = (char*)(((uintptr_t)p + 255) & ~(uintptr_t)255);
    unsigned short* rank = (unsigned short*)p;  p += (size_t)E * sizeof(unsigned short);
    p = (char*)(((uintptr_t)p + 255) & ~(uintptr_t)255);
    int2* srt = (int2*)p;             p += (size_t)E * sizeof(int2);
    size_t needed_t2 = (size_t)(p - (char*)d_ws);
    p = (char*)(((uintptr_t)p + 255) & ~(uintptr_t)255);
    unsigned int* xbf = (unsigned int*)p;  p += (size_t)N * (D / 2) * sizeof(unsigned int);
    size_t needed_t1 = (size_t)(p - (char*)d_ws);
    p = (char*)(((uintptr_t)p + 255) & ~(uintptr_t)255);
    unsigned int* aggbf = (unsigned int*)p;  p += (size_t)N * (D / 2) * sizeof(unsigned int);
    size_t needed_t0 = (size_t)(p - (char*)d_ws);

    int gemm_blocks = (N + BM - 1) / BM;

    if (ws_size >= needed_t1) {
        bool aggb = (ws_size >= needed_t0);
        prep_wbfs_kernel<<<(D * D + 255) / 256, 256, 0, stream>>>(w, wbfs);
        hipMemsetAsync(deg, 0, (size_t)N * sizeof(int), stream);
        x_to_bf16_kernel<<<2048, 256, 0, stream>>>(x, xbf, (long long)N * D / 4);
        hist_rank_kernel<<<(E + 255) / 256, 256, 0, stream>>>(ei, deg, rank, E);
        scan_blocks_kernel<<<nblk, SCAN_BLK, 0, stream>>>(deg, inscan, blksum, N);
        scan_sums_kernel<<<1, 128, 0, stream>>>(blksum, blkoff, nblk);
        finalize_offsets_kernel<<<(N + 255) / 256, 256, 0, stream>>>(deg, inscan, blkoff,
                                                                     off, N, E);
        edge_scatter2_kernel<<<(E + 255) / 256, 256, 0, stream>>>(ei, ev, off, rank, srt, E);
        if (aggb) {
            gather_bf16_kernel<true><<<(N + 3) / 4, 256, 0, stream>>>(off, srt, xbf, out,
                                                                      aggbf, N);
            linear_mfma_bf_kernel<<<gemm_blocks, 256, 0, stream>>>(aggbf, wbfs, out, N);
        } else {
            gather_bf16_kernel<false><<<(N + 3) / 4, 256, 0, stream>>>(off, srt, xbf, out,
                                                                       aggbf, N);
            linear_mfma_kernel<<<gemm_blocks, 256, 0, stream>>>(out, wbfs, N);
        }
    } else if (ws_size >= needed_t2) {
        // no bf16 table: atomic scatter of x then in-place MFMA (still correct)
        prep_wbfs_kernel<<<(D * D + 255) / 256, 256, 0, stream>>>(w, wbfs);
        hipMemsetAsync(d_out, 0, (size_t)out_size * sizeof(float), stream);
        scatter_kernel<<<4096, 256, 0, stream>>>(ei, ev, x, out, E);
        linear_mfma_kernel<<<gemm_blocks, 256, 0, stream>>>(out, wbfs, N);
    } else {
        transpose_w_kernel<<<(D * D + 255) / 256, 256, 0, stream>>>(w, wt);
        hipMemsetAsync(d_out, 0, (size_t)out_size * sizeof(float), stream);
        scatter_kernel<<<4096, 256, 0, stream>>>(ei, ev, x, out, E);
        linear_tiled_kernel<<<gemm_blocks, 256, 0, stream>>>(out, wt, N);
    }
}

// Round 11
// 207.645 us; speedup vs baseline: 6.0894x; 1.0062x over previous
//
#include <hip/hip_runtime.h>

#define D 128
#define SCAN_BLK 1024
#define BM 64
#define BM2 128
#define KC 32

using short8 = __attribute__((ext_vector_type(8))) short;
using floatx4 = __attribute__((ext_vector_type(4))) float;

__device__ __forceinline__ unsigned int f2bf(unsigned int b) {
    return (b + 0x7fffu + ((b >> 16) & 1u)) >> 16;  // RNE fp32->bf16 (as u16)
}

// ---------- W transpose (tier-3 VALU path) ----------
__global__ void transpose_w_kernel(const float* __restrict__ w, float* __restrict__ wt) {
    int t = blockIdx.x * 256 + threadIdx.x;
    if (t < D * D) {
        int o = t >> 7;
        int k = t & 127;
        wt[k * D + o] = w[t];
    }
}

// ---------- W -> bf16, XOR-swizzled [n][k] table for MFMA B-frags ----------
__global__ void prep_wbfs_kernel(const float* __restrict__ w, unsigned short* __restrict__ wbfs) {
    int t = blockIdx.x * 256 + threadIdx.x;
    if (t < D * D) {
        int n = t >> 7, k = t & 127;
        wbfs[n * 128 + (k ^ ((n & 7) << 3))] = (unsigned short)f2bf(__float_as_uint(w[t]));
    }
}

// ---------- fused: x -> bf16 pair-packed table  +  hist/rank pass ----------
// blocks [0, xblocks): grid-stride convert; blocks [xblocks, ...): 1 edge/thread.
__global__ __launch_bounds__(256) void prep_fused_kernel(const float* __restrict__ x,
                                                         unsigned int* __restrict__ xbf,
                                                         long long nvec,
                                                         const int* __restrict__ ei,
                                                         int* deg,
                                                         unsigned short* __restrict__ rank,
                                                         int E, int xblocks) {
    if ((int)blockIdx.x < xblocks) {
        long long i = (long long)blockIdx.x * 256 + threadIdx.x;
        long long stride = (long long)xblocks * 256;
        for (; i < nvec; i += stride) {
            float4 v = ((const float4*)x)[i];
            unsigned int b0 = f2bf(__float_as_uint(v.x)), b1 = f2bf(__float_as_uint(v.y));
            unsigned int b2 = f2bf(__float_as_uint(v.z)), b3 = f2bf(__float_as_uint(v.w));
            ((uint2*)xbf)[i] = make_uint2(b0 | (b1 << 16), b2 | (b3 << 16));
        }
    } else {
        int e = (blockIdx.x - xblocks) * 256 + threadIdx.x;
        if (e < E) rank[e] = (unsigned short)atomicAdd(&deg[ei[e]], 1);
    }
}

// ---------- x -> bf16 standalone (tier-2 fallback path) ----------
__global__ __launch_bounds__(256) void x_to_bf16_kernel(const float* __restrict__ x,
                                                        unsigned int* __restrict__ xbf,
                                                        long long nvec) {
    long long i = (long long)blockIdx.x * 256 + threadIdx.x;
    long long stride = (long long)gridDim.x * 256;
    for (; i < nvec; i += stride) {
        float4 v = ((const float4*)x)[i];
        unsigned int b0 = f2bf(__float_as_uint(v.x)), b1 = f2bf(__float_as_uint(v.y));
        unsigned int b2 = f2bf(__float_as_uint(v.z)), b3 = f2bf(__float_as_uint(v.w));
        ((uint2*)xbf)[i] = make_uint2(b0 | (b1 << 16), b2 | (b3 << 16));
    }
}

// ---------- scans ----------
__global__ __launch_bounds__(SCAN_BLK) void scan_blocks_kernel(const int* __restrict__ deg,
                                                               int* inscan, int* blksum, int n) {
    __shared__ int s[SCAN_BLK];
    int gid = blockIdx.x * SCAN_BLK + threadIdx.x;
    int v = (gid < n) ? deg[gid] : 0;
    s[threadIdx.x] = v;
    __syncthreads();
    for (int d = 1; d < SCAN_BLK; d <<= 1) {
        int t = (threadIdx.x >= d) ? s[threadIdx.x - d] : 0;
        __syncthreads();
        s[threadIdx.x] += t;
        __syncthreads();
    }
    if (gid < n) inscan[gid] = s[threadIdx.x];
    if (threadIdx.x == SCAN_BLK - 1) blksum[blockIdx.x] = s[SCAN_BLK - 1];
}

__global__ __launch_bounds__(128) void scan_sums_kernel(const int* __restrict__ blksum,
                                                        int* blkoff, int nblk) {
    __shared__ int s[128];
    int v = (threadIdx.x < nblk) ? blksum[threadIdx.x] : 0;
    s[threadIdx.x] = v;
    __syncthreads();
    for (int d = 1; d < 128; d <<= 1) {
        int t = (threadIdx.x >= d) ? s[threadIdx.x - d] : 0;
        __syncthreads();
        s[threadIdx.x] += t;
        __syncthreads();
    }
    if (threadIdx.x < nblk) blkoff[threadIdx.x] = s[threadIdx.x] - v;
}

__global__ void finalize_offsets_kernel(const int* __restrict__ deg,
                                        const int* __restrict__ inscan,
                                        const int* __restrict__ blkoff,
                                        int* off, int n, int E) {
    int gid = blockIdx.x * 256 + threadIdx.x;
    if (gid < n) off[gid] = blkoff[gid >> 10] + inscan[gid] - deg[gid];  // exclusive
    if (gid == 0) off[n] = E;
}

// ---------- reorder edges, no atomics: pos = off[dst] + rank[e] ----------
__global__ void edge_scatter2_kernel(const int* __restrict__ ei, const float* __restrict__ ev,
                                     const int* __restrict__ off,
                                     const unsigned short* __restrict__ rank,
                                     int2* __restrict__ srt, int E) {
    int e = blockIdx.x * 256 + threadIdx.x;
    if (e < E) {
        int dst = ei[e];
        int pos = off[dst] + (int)rank[e];
        srt[pos] = make_int2(ei[E + e], __float_as_int(ev[e]));
    }
}

// ---------- CSR gather from bf16 table; AGGBF: emit packed-bf16 agg ----------
template <bool AGGBF>
__global__ __launch_bounds__(256) void gather_bf16_kernel(const int* __restrict__ off,
                                                          const int2* __restrict__ srt,
                                                          const unsigned int* __restrict__ xbf,
                                                          float* __restrict__ out,
                                                          unsigned int* __restrict__ aggbf,
                                                          int N) {
    int lane = threadIdx.x & 63;
    int wid = blockIdx.x * 4 + (threadIdx.x >> 6);
    if (wid >= N) return;
    int beg = off[wid], end = off[wid + 1];
    float2 acc = make_float2(0.f, 0.f);
    int e = beg;
    for (; e + 3 < end; e += 4) {
        int2 s0 = srt[e], s1 = srt[e + 1], s2 = srt[e + 2], s3 = srt[e + 3];
        unsigned int u0 = xbf[(size_t)s0.x * 64 + lane];
        unsigned int u1 = xbf[(size_t)s1.x * 64 + lane];
        unsigned int u2 = xbf[(size_t)s2.x * 64 + lane];
        unsigned int u3 = xbf[(size_t)s3.x * 64 + lane];
        float v0 = __int_as_float(s0.y), v1 = __int_as_float(s1.y);
        float v2 = __int_as_float(s2.y), v3 = __int_as_float(s3.y);
        acc.x = fmaf(v0, __uint_as_float(u0 << 16), acc.x);
        acc.y = fmaf(v0, __uint_as_float(u0 & 0xffff0000u), acc.y);
        acc.x = fmaf(v1, __uint_as_float(u1 << 16), acc.x);
        acc.y = fmaf(v1, __uint_as_float(u1 & 0xffff0000u), acc.y);
        acc.x = fmaf(v2, __uint_as_float(u2 << 16), acc.x);
        acc.y = fmaf(v2, __uint_as_float(u2 & 0xffff0000u), acc.y);
        acc.x = fmaf(v3, __uint_as_float(u3 << 16), acc.x);
        acc.y = fmaf(v3, __uint_as_float(u3 & 0xffff0000u), acc.y);
    }
    for (; e < end; ++e) {
        int2 sv = srt[e];
        unsigned int u = xbf[(size_t)sv.x * 64 + lane];
        float v = __int_as_float(sv.y);
        acc.x = fmaf(v, __uint_as_float(u << 16), acc.x);
        acc.y = fmaf(v, __uint_as_float(u & 0xffff0000u), acc.y);
    }
    if (AGGBF) {
        unsigned int pk = f2bf(__float_as_uint(acc.x)) | (f2bf(__float_as_uint(acc.y)) << 16);
        aggbf[(size_t)wid * 64 + lane] = pk;
    } else {
        *(float2*)&out[(size_t)wid * D + lane * 2] = acc;
    }
}

// ---------- MFMA linear, BM2=128 rows/block, 8 waves, A from packed-bf16 agg ----------
__global__ __launch_bounds__(512) void linear_mfma_bf2_kernel(const unsigned int* __restrict__ aggbf,
                                                              const unsigned short* __restrict__ wbfs,
                                                              float* __restrict__ out, int N) {
    __shared__ __align__(16) unsigned short sW[D * D];     // 32 KiB, swizzled [n][k]
    __shared__ __align__(16) unsigned short sA[BM2 * D];   // 32 KiB, swizzled [m][k]
    int t = threadIdx.x;
    int row0 = blockIdx.x * BM2;
    {
        const uint4* src = (const uint4*)wbfs;
        uint4* dst = (uint4*)sW;
#pragma unroll
        for (int i = 0; i < 4; ++i) dst[i * 512 + t] = src[i * 512 + t];
    }
#pragma unroll
    for (int it = 0; it < 4; ++it) {
        int iv = it * 512 + t;  // uint4 id 0..2047
        int m = iv >> 4;        // row 0..127
        int q = iv & 15;        // 16B chunk in row
        int r = row0 + m;
        int rcl = r < N ? r : N - 1;
        uint4 v = *(const uint4*)&aggbf[(size_t)rcl * 64 + q * 4];
        *(uint4*)((char*)sA + m * 256 + ((q * 16) ^ ((m & 7) << 4))) = v;
    }
    __syncthreads();

    int lane = t & 63;
    int w = t >> 6;             // 0..7
    int lm = 16 * w + (lane & 15);
    int ln = lane & 15;
    int kg = lane >> 4;

    floatx4 acc[8];
#pragma unroll
    for (int nt = 0; nt < 8; ++nt) acc[nt] = (floatx4){0.f, 0.f, 0.f, 0.f};

#pragma unroll
    for (int ks = 0; ks < 4; ++ks) {
        int kbyte = ks * 64 + kg * 16;
        short8 a = *(const short8*)((const char*)sA + lm * 256 + (kbyte ^ ((lm & 7) << 4)));
#pragma unroll
        for (int nt = 0; nt < 8; ++nt) {
            int n = nt * 16 + ln;
            short8 bfr = *(const short8*)((const char*)sW + n * 256 + (kbyte ^ ((n & 7) << 4)));
            acc[nt] = __builtin_amdgcn_mfma_f32_16x16x32_bf16(a, bfr, acc[nt], 0, 0, 0);
        }
    }

    int rbase = row0 + 16 * w + 4 * kg;
#pragma unroll
    for (int nt = 0; nt < 8; ++nt) {
#pragma unroll
        for (int r = 0; r < 4; ++r) {
            int row = rbase + r;
            if (row < N) out[(size_t)row * D + nt * 16 + ln] = acc[nt][r];
        }
    }
}

// ---------- MFMA linear in-place from fp32 io (tier-2 fallback) ----------
__global__ __launch_bounds__(256) void linear_mfma_kernel(float* io,
                                                          const unsigned short* __restrict__ wbfs,
                                                          int N) {
    __shared__ __align__(16) unsigned short sW[D * D];
    __shared__ __align__(16) unsigned short sA[BM * D];
    int t = threadIdx.x;
    int row0 = blockIdx.x * BM;
    {
        const uint4* src = (const uint4*)wbfs;
        uint4* dst = (uint4*)sW;
#pragma unroll
        for (int i = 0; i < 8; ++i) dst[i * 256 + t] = src[i * 256 + t];
    }
#pragma unroll
    for (int it = 0; it < 8; ++it) {
        int idx = it * 1024 + t * 4;
        int m = idx >> 7;
        int k0 = idx & 127;
        int r = row0 + m;
        int rcl = r < N ? r : N - 1;
        float4 v = *(const float4*)&io[(size_t)rcl * D + k0];
        unsigned int b0 = f2bf(__float_as_uint(v.x)), b1 = f2bf(__float_as_uint(v.y));
        unsigned int b2 = f2bf(__float_as_uint(v.z)), b3 = f2bf(__float_as_uint(v.w));
        int byteoff = m * 256 + ((k0 * 2) ^ ((m & 7) << 4));
        *(uint2*)((char*)sA + byteoff) = make_uint2(b0 | (b1 << 16), b2 | (b3 << 16));
    }
    __syncthreads();

    int lane = t & 63;
    int w = t >> 6;
    int lm = 16 * w + (lane & 15);
    int ln = lane & 15;
    int kg = lane >> 4;

    floatx4 acc[8];
#pragma unroll
    for (int nt = 0; nt < 8; ++nt) acc[nt] = (floatx4){0.f, 0.f, 0.f, 0.f};

#pragma unroll
    for (int ks = 0; ks < 4; ++ks) {
        int kbyte = ks * 64 + kg * 16;
        short8 a = *(const short8*)((const char*)sA + lm * 256 + (kbyte ^ ((lm & 7) << 4)));
#pragma unroll
        for (int nt = 0; nt < 8; ++nt) {
            int n = nt * 16 + ln;
            short8 bfr = *(const short8*)((const char*)sW + n * 256 + (kbyte ^ ((n & 7) << 4)));
            acc[nt] = __builtin_amdgcn_mfma_f32_16x16x32_bf16(a, bfr, acc[nt], 0, 0, 0);
        }
    }

    int rbase = row0 + 16 * w + 4 * kg;
#pragma unroll
    for (int nt = 0; nt < 8; ++nt) {
#pragma unroll
        for (int r = 0; r < 4; ++r) {
            int row = rbase + r;
            if (row < N) io[(size_t)row * D + nt * 16 + ln] = acc[nt][r];
        }
    }
}

// ---------- tier-3 fallbacks ----------
__global__ __launch_bounds__(256) void scatter_kernel(const int* __restrict__ ei,
                                                      const float* __restrict__ ev,
                                                      const float* __restrict__ x,
                                                      float* agg, int E) {
    int lane = threadIdx.x & 63;
    long long wid = (long long)blockIdx.x * 4 + (threadIdx.x >> 6);
    long long nw = (long long)gridDim.x * 4;
    for (long long e = wid; e < E; e += nw) {
        int i = ei[e];
        int j = ei[(long long)E + e];
        float v = ev[e];
        float2 xv = *(const float2*)&x[(size_t)j * D + lane * 2];
        float* op = &agg[(size_t)i * D + lane * 2];
        unsafeAtomicAdd(&op[0], v * xv.x);
        unsafeAtomicAdd(&op[1], v * xv.y);
    }
}

__global__ __launch_bounds__(256) void linear_tiled_kernel(float* io,
                                                           const float* __restrict__ wt,
                                                           int N) {
    __shared__ float sA[KC][BM + 4];
    __shared__ float sW2[KC][D];
    int t = threadIdx.x;
    int tc = t & 15;
    int tr = t >> 4;
    int row0 = blockIdx.x * BM;

    float acc[4][8];
#pragma unroll
    for (int i = 0; i < 4; ++i)
#pragma unroll
        for (int j = 0; j < 8; ++j) acc[i][j] = 0.f;

    int ldA_r = t >> 3;
    int ldA_k = (t & 7) * 4;
    int ldW_k = t >> 5;
    int ldW_c = (t & 31) * 4;

    for (int kc = 0; kc < D; kc += KC) {
#pragma unroll
        for (int rr = 0; rr < BM; rr += 32) {
            int r = row0 + ldA_r + rr;
            int rcl = r < N ? r : N - 1;
            float4 v = *(const float4*)&io[(size_t)rcl * D + kc + ldA_k];
            sA[ldA_k + 0][ldA_r + rr] = v.x;
            sA[ldA_k + 1][ldA_r + rr] = v.y;
            sA[ldA_k + 2][ldA_r + rr] = v.z;
            sA[ldA_k + 3][ldA_r + rr] = v.w;
        }
#pragma unroll
        for (int kk = 0; kk < KC; kk += 8)
            *(float4*)&sW2[ldW_k + kk][ldW_c] =
                *(const float4*)&wt[(size_t)(kc + ldW_k + kk) * D + ldW_c];
        __syncthreads();

#pragma unroll 8
        for (int k = 0; k < KC; ++k) {
            float4 a = *(const float4*)&sA[k][tr * 4];
            float4 w0 = *(const float4*)&sW2[k][tc * 8];
            float4 w1 = *(const float4*)&sW2[k][tc * 8 + 4];
            float av[4] = {a.x, a.y, a.z, a.w};
            float wv[8] = {w0.x, w0.y, w0.z, w0.w, w1.x, w1.y, w1.z, w1.w};
#pragma unroll
            for (int i = 0; i < 4; ++i)
#pragma unroll
                for (int j = 0; j < 8; ++j)
                    acc[i][j] = fmaf(av[i], wv[j], acc[i][j]);
        }
        __syncthreads();
    }

#pragma unroll
    for (int i = 0; i < 4; ++i) {
        int r = row0 + tr * 4 + i;
        if (r < N) {
            *(float4*)&io[(size_t)r * D + tc * 8] = *(float4*)&acc[i][0];
            *(float4*)&io[(size_t)r * D + tc * 8 + 4] = *(float4*)&acc[i][4];
        }
    }
}

extern "C" void kernel_launch(void* const* d_in, const int* in_sizes, int n_in,
                              void* d_out, int out_size, void* d_ws, size_t ws_size,
                              hipStream_t stream) {
    const float* x = (const float*)d_in[0];
    const float* w = (const float*)d_in[1];
    const int* ei = (const int*)d_in[2];   // [2,E] int32 (dst row, then src row)
    const float* ev = (const float*)d_in[3];

    int N = in_sizes[0] / D;
    int E = in_sizes[3];
    int nblk = (N + SCAN_BLK - 1) / SCAN_BLK;

    float* out = (float*)d_out;

    // workspace layout (progressive tiers)
    char* p = (char*)d_ws;
    float* wt = (float*)p;            p += (size_t)D * D * sizeof(float);
    unsigned short* wbfs = (unsigned short*)p;  p += (size_t)D * D * sizeof(unsigned short);
    int* deg = (int*)p;               p += (size_t)N * sizeof(int);
    int* inscan = (int*)p;            p += (size_t)N * sizeof(int);
    int* off = (int*)p;               p += (size_t)(N + 1) * sizeof(int);
    int* blksum = (int*)p;            p += (size_t)nblk * sizeof(int);
    int* blkoff = (int*)p;            p += (size_t)nblk * sizeof(int);
    p = (char*)(((uintptr_t)p + 255) & ~(uintptr_t)255);
    unsigned short* rank = (unsigned short*)p;  p += (size_t)E * sizeof(unsigned short);
    p = (char*)(((uintptr_t)p + 255) & ~(uintptr_t)255);
    int2* srt = (int2*)p;             p += (size_t)E * sizeof(int2);
    size_t needed_t2 = (size_t)(p - (char*)d_ws);
    p = (char*)(((uintptr_t)p + 255) & ~(uintptr_t)255);
    unsigned int* xbf = (unsigned int*)p;  p += (size_t)N * (D / 2) * sizeof(unsigned int);
    size_t needed_t1 = (size_t)(p - (char*)d_ws);
    p = (char*)(((uintptr_t)p + 255) & ~(uintptr_t)255);
    unsigned int* aggbf = (unsigned int*)p;  p += (size_t)N * (D / 2) * sizeof(unsigned int);
    size_t needed_t0 = (size_t)(p - (char*)d_ws);

    if (ws_size >= needed_t1) {
        bool aggb = (ws_size >= needed_t0);
        const int xblocks = 2048;
        prep_wbfs_kernel<<<(D * D + 255) / 256, 256, 0, stream>>>(w, wbfs);
        hipMemsetAsync(deg, 0, (size_t)N * sizeof(int), stream);
        prep_fused_kernel<<<xblocks + (E + 255) / 256, 256, 0, stream>>>(
            x, xbf, (long long)N * D / 4, ei, deg, rank, E, xblocks);
        scan_blocks_kernel<<<nblk, SCAN_BLK, 0, stream>>>(deg, inscan, blksum, N);
        scan_sums_kernel<<<1, 128, 0, stream>>>(blksum, blkoff, nblk);
        finalize_offsets_kernel<<<(N + 255) / 256, 256, 0, stream>>>(deg, inscan, blkoff,
                                                                     off, N, E);
        edge_scatter2_kernel<<<(E + 255) / 256, 256, 0, stream>>>(ei, ev, off, rank, srt, E);
        if (aggb) {
            gather_bf16_kernel<true><<<(N + 3) / 4, 256, 0, stream>>>(off, srt, xbf, out,
                                                                      aggbf, N);
            linear_mfma_bf2_kernel<<<(N + BM2 - 1) / BM2, 512, 0, stream>>>(aggbf, wbfs, out, N);
        } else {
            gather_bf16_kernel<false><<<(N + 3) / 4, 256, 0, stream>>>(off, srt, xbf, out,
                                                                       aggbf, N);
            linear_mfma_kernel<<<(N + BM - 1) / BM, 256, 0, stream>>>(out, wbfs, N);
        }
    } else if (ws_size >= needed_t2) {
        prep_wbfs_kernel<<<(D * D + 255) / 256, 256, 0, stream>>>(w, wbfs);
        hipMemsetAsync(d_out, 0, (size_t)out_size * sizeof(float), stream);
        scatter_kernel<<<4096, 256, 0, stream>>>(ei, ev, x, out, E);
        linear_mfma_kernel<<<(N + BM - 1) / BM, 256, 0, stream>>>(out, wbfs, N);
    } else {
        transpose_w_kernel<<<(D * D + 255) / 256, 256, 0, stream>>>(w, wt);
        hipMemsetAsync(d_out, 0, (size_t)out_size * sizeof(float), stream);
        scatter_kernel<<<4096, 256, 0, stream>>>(ei, ev, x, out, E);
        linear_tiled_kernel<<<(N + BM - 1) / BM, 256, 0, stream>>>(out, wt, N);
    }
}

// Round 12
// 169.198 us; speedup vs baseline: 7.4730x; 1.2272x over previous
//
#include <hip/hip_runtime.h>

#define D 128
#define SCAN_BLK 1024
#define BM 64
#define BM2 128
#define KC 32
#define BSH 6
#define BNODES 64

using short8 = __attribute__((ext_vector_type(8))) short;
using floatx4 = __attribute__((ext_vector_type(4))) float;

__device__ __forceinline__ unsigned int f2bf(unsigned int b) {
    return (b + 0x7fffu + ((b >> 16) & 1u)) >> 16;  // RNE fp32->bf16 (as u16)
}

// ---------- W transpose (tier-3 VALU path) ----------
__global__ void transpose_w_kernel(const float* __restrict__ w, float* __restrict__ wt) {
    int t = blockIdx.x * 256 + threadIdx.x;
    if (t < D * D) {
        int o = t >> 7;
        int k = t & 127;
        wt[k * D + o] = w[t];
    }
}

// ---------- W -> bf16, XOR-swizzled [n][k] table for MFMA B-frags ----------
__global__ void prep_wbfs_kernel(const float* __restrict__ w, unsigned short* __restrict__ wbfs) {
    int t = blockIdx.x * 256 + threadIdx.x;
    if (t < D * D) {
        int n = t >> 7, k = t & 127;
        wbfs[n * 128 + (k ^ ((n & 7) << 3))] = (unsigned short)f2bf(__float_as_uint(w[t]));
    }
}

// ---------- x -> bf16 pair packing ----------
__global__ __launch_bounds__(256) void x_to_bf16_kernel(const float* __restrict__ x,
                                                        unsigned int* __restrict__ xbf,
                                                        long long nvec) {
    long long i = (long long)blockIdx.x * 256 + threadIdx.x;
    long long stride = (long long)gridDim.x * 256;
    for (; i < nvec; i += stride) {
        float4 v = ((const float4*)x)[i];
        unsigned int b0 = f2bf(__float_as_uint(v.x)), b1 = f2bf(__float_as_uint(v.y));
        unsigned int b2 = f2bf(__float_as_uint(v.z)), b3 = f2bf(__float_as_uint(v.w));
        ((uint2*)xbf)[i] = make_uint2(b0 | (b1 << 16), b2 | (b3 << 16));
    }
}

// ---------- bucket histogram (64-node buckets); non-returning atomics only ----------
__global__ __launch_bounds__(512) void bhist_kernel(const int* __restrict__ ei, int* bhist,
                                                    int E, int NB) {
    __shared__ int h[2048];
    int tid = threadIdx.x;
    for (int i = tid; i < NB; i += 512) h[i] = 0;
    __syncthreads();
    for (long long e = (long long)blockIdx.x * 512 + tid; e < E; e += (long long)gridDim.x * 512)
        atomicAdd(&h[((unsigned)ei[e]) >> BSH], 1);
    __syncthreads();
    for (int i = tid; i < NB; i += 512)
        if (h[i]) atomicAdd(&bhist[i], h[i]);
}

// ---------- scans ----------
__global__ __launch_bounds__(SCAN_BLK) void scan_blocks_kernel(const int* __restrict__ deg,
                                                               int* inscan, int* blksum, int n) {
    __shared__ int s[SCAN_BLK];
    int gid = blockIdx.x * SCAN_BLK + threadIdx.x;
    int v = (gid < n) ? deg[gid] : 0;
    s[threadIdx.x] = v;
    __syncthreads();
    for (int d = 1; d < SCAN_BLK; d <<= 1) {
        int t = (threadIdx.x >= d) ? s[threadIdx.x - d] : 0;
        __syncthreads();
        s[threadIdx.x] += t;
        __syncthreads();
    }
    if (gid < n) inscan[gid] = s[threadIdx.x];
    if (threadIdx.x == SCAN_BLK - 1) blksum[blockIdx.x] = s[SCAN_BLK - 1];
}

__global__ __launch_bounds__(128) void scan_sums_kernel(const int* __restrict__ blksum,
                                                        int* blkoff, int nblk) {
    __shared__ int s[128];
    int v = (threadIdx.x < nblk) ? blksum[threadIdx.x] : 0;
    s[threadIdx.x] = v;
    __syncthreads();
    for (int d = 1; d < 128; d <<= 1) {
        int t = (threadIdx.x >= d) ? s[threadIdx.x - d] : 0;
        __syncthreads();
        s[threadIdx.x] += t;
        __syncthreads();
    }
    if (threadIdx.x < nblk) blkoff[threadIdx.x] = s[threadIdx.x] - v;
}

// bbase/bcursor from bucket scan; also off[N] = E (gather's last segment end)
__global__ void bucket_finalize_kernel(const int* __restrict__ bhist,
                                       const int* __restrict__ binscan,
                                       const int* __restrict__ bblkoff,
                                       int* bbase, int* bcursor, int* off,
                                       int NB, int N, int E) {
    int g = blockIdx.x * 256 + threadIdx.x;
    if (g < NB) {
        int o = bblkoff[g >> 10] + binscan[g] - bhist[g];  // exclusive
        bbase[g] = o;
        bcursor[g] = o;
    }
    if (g == 0) { bbase[NB] = E; off[N] = E; }
}

// ---------- binA: partition edges into 64-node buckets (order-free) ----------
// pack: src (26b) | dst_local (6b) << 26
__global__ __launch_bounds__(512) void binA_kernel(const int* __restrict__ ei,
                                                   const float* __restrict__ ev,
                                                   int* bcursor, int2* __restrict__ ebin,
                                                   int E, int NB) {
    __shared__ int hist[2048];
    __shared__ int base[2048];
    __shared__ int cnt2[2048];
    int tid = threadIdx.x;
    for (int i = tid; i < NB; i += 512) { hist[i] = 0; cnt2[i] = 0; }
    __syncthreads();
    int e0 = blockIdx.x * 8192;
#pragma unroll
    for (int i = 0; i < 16; ++i) {
        int e = e0 + i * 512 + tid;
        if (e < E) atomicAdd(&hist[((unsigned)ei[e]) >> BSH], 1);
    }
    __syncthreads();
    for (int i = tid; i < NB; i += 512)
        if (hist[i]) base[i] = atomicAdd(&bcursor[i], hist[i]);
    __syncthreads();
#pragma unroll
    for (int i = 0; i < 16; ++i) {
        int e = e0 + i * 512 + tid;
        if (e < E) {
            int dst = ei[e];
            int b = ((unsigned)dst) >> BSH;
            int pos = base[b] + atomicAdd(&cnt2[b], 1);
            ebin[pos] = make_int2(ei[E + e] | ((dst & (BNODES - 1)) << 26),
                                  __float_as_int(ev[e]));
        }
    }
}

// ---------- binB2: per-bucket exact CSR (deg count + local scan) -> off + srt ----------
// One block per bucket; all atomics are fast LDS; srt writes confined to the
// bucket's contiguous ~32KB window (write-amp ~1).  Replaces the node-level
// hist_rank (1.6M returning GLOBAL atomics, ~70us) entirely.
__global__ __launch_bounds__(512) void binB2_kernel(const int* __restrict__ bbase,
                                                    const int2* __restrict__ ebin,
                                                    int* __restrict__ off,
                                                    int2* __restrict__ srt, int N) {
    __shared__ int degL[BNODES];
    __shared__ int cum[BNODES];
    __shared__ int cnt2[BNODES];
    int b = blockIdx.x;
    int tid = threadIdx.x;
    if (tid < BNODES) { degL[tid] = 0; cnt2[tid] = 0; }
    __syncthreads();
    int start = bbase[b], end = bbase[b + 1];
    for (int p = start + tid; p < end; p += 512)
        atomicAdd(&degL[((unsigned)ebin[p].x) >> 26], 1);
    __syncthreads();
    if (tid == 0) {
        int run = start;
#pragma unroll
        for (int i = 0; i < BNODES; ++i) { cum[i] = run; run += degL[i]; }
    }
    __syncthreads();
    int node0 = b << BSH;
    if (tid < BNODES && node0 + tid < N) off[node0 + tid] = cum[tid];
    for (int p = start + tid; p < end; p += 512) {
        int2 eb = ebin[p];
        int dl = ((unsigned)eb.x) >> 26;
        int pos = cum[dl] + atomicAdd(&cnt2[dl], 1);
        srt[pos] = make_int2(eb.x & 0x03FFFFFF, eb.y);
    }
}

// ---------- tier-2 fallback CSR machinery (R10-proven) ----------
__global__ void hist_rank_kernel(const int* __restrict__ ei, int* deg,
                                 unsigned short* __restrict__ rank, int E) {
    int e = blockIdx.x * 256 + threadIdx.x;
    if (e < E) rank[e] = (unsigned short)atomicAdd(&deg[ei[e]], 1);
}

__global__ void finalize_offsets_kernel(const int* __restrict__ deg,
                                        const int* __restrict__ inscan,
                                        const int* __restrict__ blkoff,
                                        int* off, int n, int E) {
    int gid = blockIdx.x * 256 + threadIdx.x;
    if (gid < n) off[gid] = blkoff[gid >> 10] + inscan[gid] - deg[gid];
    if (gid == 0) off[n] = E;
}

__global__ void edge_scatter2_kernel(const int* __restrict__ ei, const float* __restrict__ ev,
                                     const int* __restrict__ off,
                                     const unsigned short* __restrict__ rank,
                                     int2* __restrict__ srt, int E) {
    int e = blockIdx.x * 256 + threadIdx.x;
    if (e < E) {
        int dst = ei[e];
        int pos = off[dst] + (int)rank[e];
        srt[pos] = make_int2(ei[E + e], __float_as_int(ev[e]));
    }
}

// ---------- CSR gather from bf16 table; AGGBF: emit packed-bf16 agg ----------
template <bool AGGBF>
__global__ __launch_bounds__(256) void gather_bf16_kernel(const int* __restrict__ off,
                                                          const int2* __restrict__ srt,
                                                          const unsigned int* __restrict__ xbf,
                                                          float* __restrict__ out,
                                                          unsigned int* __restrict__ aggbf,
                                                          int N) {
    int lane = threadIdx.x & 63;
    int wid = blockIdx.x * 4 + (threadIdx.x >> 6);
    if (wid >= N) return;
    int beg = off[wid], end = off[wid + 1];
    float2 acc = make_float2(0.f, 0.f);
    int e = beg;
    for (; e + 3 < end; e += 4) {
        int2 s0 = srt[e], s1 = srt[e + 1], s2 = srt[e + 2], s3 = srt[e + 3];
        unsigned int u0 = xbf[(size_t)s0.x * 64 + lane];
        unsigned int u1 = xbf[(size_t)s1.x * 64 + lane];
        unsigned int u2 = xbf[(size_t)s2.x * 64 + lane];
        unsigned int u3 = xbf[(size_t)s3.x * 64 + lane];
        float v0 = __int_as_float(s0.y), v1 = __int_as_float(s1.y);
        float v2 = __int_as_float(s2.y), v3 = __int_as_float(s3.y);
        acc.x = fmaf(v0, __uint_as_float(u0 << 16), acc.x);
        acc.y = fmaf(v0, __uint_as_float(u0 & 0xffff0000u), acc.y);
        acc.x = fmaf(v1, __uint_as_float(u1 << 16), acc.x);
        acc.y = fmaf(v1, __uint_as_float(u1 & 0xffff0000u), acc.y);
        acc.x = fmaf(v2, __uint_as_float(u2 << 16), acc.x);
        acc.y = fmaf(v2, __uint_as_float(u2 & 0xffff0000u), acc.y);
        acc.x = fmaf(v3, __uint_as_float(u3 << 16), acc.x);
        acc.y = fmaf(v3, __uint_as_float(u3 & 0xffff0000u), acc.y);
    }
    for (; e < end; ++e) {
        int2 sv = srt[e];
        unsigned int u = xbf[(size_t)sv.x * 64 + lane];
        float v = __int_as_float(sv.y);
        acc.x = fmaf(v, __uint_as_float(u << 16), acc.x);
        acc.y = fmaf(v, __uint_as_float(u & 0xffff0000u), acc.y);
    }
    if (AGGBF) {
        unsigned int pk = f2bf(__float_as_uint(acc.x)) | (f2bf(__float_as_uint(acc.y)) << 16);
        aggbf[(size_t)wid * 64 + lane] = pk;
    } else {
        *(float2*)&out[(size_t)wid * D + lane * 2] = acc;
    }
}

// ---------- MFMA linear, BM2=128 rows/block, 8 waves, A from packed-bf16 agg ----------
__global__ __launch_bounds__(512) void linear_mfma_bf2_kernel(const unsigned int* __restrict__ aggbf,
                                                              const unsigned short* __restrict__ wbfs,
                                                              float* __restrict__ out, int N) {
    __shared__ __align__(16) unsigned short sW[D * D];
    __shared__ __align__(16) unsigned short sA[BM2 * D];
    int t = threadIdx.x;
    int row0 = blockIdx.x * BM2;
    {
        const uint4* src = (const uint4*)wbfs;
        uint4* dst = (uint4*)sW;
#pragma unroll
        for (int i = 0; i < 4; ++i) dst[i * 512 + t] = src[i * 512 + t];
    }
#pragma unroll
    for (int it = 0; it < 4; ++it) {
        int iv = it * 512 + t;
        int m = iv >> 4;
        int q = iv & 15;
        int r = row0 + m;
        int rcl = r < N ? r : N - 1;
        uint4 v = *(const uint4*)&aggbf[(size_t)rcl * 64 + q * 4];
        *(uint4*)((char*)sA + m * 256 + ((q * 16) ^ ((m & 7) << 4))) = v;
    }
    __syncthreads();

    int lane = t & 63;
    int w = t >> 6;
    int lm = 16 * w + (lane & 15);
    int ln = lane & 15;
    int kg = lane >> 4;

    floatx4 acc[8];
#pragma unroll
    for (int nt = 0; nt < 8; ++nt) acc[nt] = (floatx4){0.f, 0.f, 0.f, 0.f};

#pragma unroll
    for (int ks = 0; ks < 4; ++ks) {
        int kbyte = ks * 64 + kg * 16;
        short8 a = *(const short8*)((const char*)sA + lm * 256 + (kbyte ^ ((lm & 7) << 4)));
#pragma unroll
        for (int nt = 0; nt < 8; ++nt) {
            int n = nt * 16 + ln;
            short8 bfr = *(const short8*)((const char*)sW + n * 256 + (kbyte ^ ((n & 7) << 4)));
            acc[nt] = __builtin_amdgcn_mfma_f32_16x16x32_bf16(a, bfr, acc[nt], 0, 0, 0);
        }
    }

    int rbase = row0 + 16 * w + 4 * kg;
#pragma unroll
    for (int nt = 0; nt < 8; ++nt) {
#pragma unroll
        for (int r = 0; r < 4; ++r) {
            int row = rbase + r;
            if (row < N) out[(size_t)row * D + nt * 16 + ln] = acc[nt][r];
        }
    }
}

// ---------- MFMA linear in-place from fp32 io (tier-2 fallback) ----------
__global__ __launch_bounds__(256) void linear_mfma_kernel(float* io,
                                                          const unsigned short* __restrict__ wbfs,
                                                          int N) {
    __shared__ __align__(16) unsigned short sW[D * D];
    __shared__ __align__(16) unsigned short sA[BM * D];
    int t = threadIdx.x;
    int row0 = blockIdx.x * BM;
    {
        const uint4* src = (const uint4*)wbfs;
        uint4* dst = (uint4*)sW;
#pragma unroll
        for (int i = 0; i < 8; ++i) dst[i * 256 + t] = src[i * 256 + t];
    }
#pragma unroll
    for (int it = 0; it < 8; ++it) {
        int idx = it * 1024 + t * 4;
        int m = idx >> 7;
        int k0 = idx & 127;
        int r = row0 + m;
        int rcl = r < N ? r : N - 1;
        float4 v = *(const float4*)&io[(size_t)rcl * D + k0];
        unsigned int b0 = f2bf(__float_as_uint(v.x)), b1 = f2bf(__float_as_uint(v.y));
        unsigned int b2 = f2bf(__float_as_uint(v.z)), b3 = f2bf(__float_as_uint(v.w));
        int byteoff = m * 256 + ((k0 * 2) ^ ((m & 7) << 4));
        *(uint2*)((char*)sA + byteoff) = make_uint2(b0 | (b1 << 16), b2 | (b3 << 16));
    }
    __syncthreads();

    int lane = t & 63;
    int w = t >> 6;
    int lm = 16 * w + (lane & 15);
    int ln = lane & 15;
    int kg = lane >> 4;

    floatx4 acc[8];
#pragma unroll
    for (int nt = 0; nt < 8; ++nt) acc[nt] = (floatx4){0.f, 0.f, 0.f, 0.f};

#pragma unroll
    for (int ks = 0; ks < 4; ++ks) {
        int kbyte = ks * 64 + kg * 16;
        short8 a = *(const short8*)((const char*)sA + lm * 256 + (kbyte ^ ((lm & 7) << 4)));
#pragma unroll
        for (int nt = 0; nt < 8; ++nt) {
            int n = nt * 16 + ln;
            short8 bfr = *(const short8*)((const char*)sW + n * 256 + (kbyte ^ ((n & 7) << 4)));
            acc[nt] = __builtin_amdgcn_mfma_f32_16x16x32_bf16(a, bfr, acc[nt], 0, 0, 0);
        }
    }

    int rbase = row0 + 16 * w + 4 * kg;
#pragma unroll
    for (int nt = 0; nt < 8; ++nt) {
#pragma unroll
        for (int r = 0; r < 4; ++r) {
            int row = rbase + r;
            if (row < N) io[(size_t)row * D + nt * 16 + ln] = acc[nt][r];
        }
    }
}

// ---------- tier-3 fallbacks ----------
__global__ __launch_bounds__(256) void scatter_kernel(const int* __restrict__ ei,
                                                      const float* __restrict__ ev,
                                                      const float* __restrict__ x,
                                                      float* agg, int E) {
    int lane = threadIdx.x & 63;
    long long wid = (long long)blockIdx.x * 4 + (threadIdx.x >> 6);
    long long nw = (long long)gridDim.x * 4;
    for (long long e = wid; e < E; e += nw) {
        int i = ei[e];
        int j = ei[(long long)E + e];
        float v = ev[e];
        float2 xv = *(const float2*)&x[(size_t)j * D + lane * 2];
        float* op = &agg[(size_t)i * D + lane * 2];
        unsafeAtomicAdd(&op[0], v * xv.x);
        unsafeAtomicAdd(&op[1], v * xv.y);
    }
}

__global__ __launch_bounds__(256) void linear_tiled_kernel(float* io,
                                                           const float* __restrict__ wt,
                                                           int N) {
    __shared__ float sA[KC][BM + 4];
    __shared__ float sW2[KC][D];
    int t = threadIdx.x;
    int tc = t & 15;
    int tr = t >> 4;
    int row0 = blockIdx.x * BM;

    float acc[4][8];
#pragma unroll
    for (int i = 0; i < 4; ++i)
#pragma unroll
        for (int j = 0; j < 8; ++j) acc[i][j] = 0.f;

    int ldA_r = t >> 3;
    int ldA_k = (t & 7) * 4;
    int ldW_k = t >> 5;
    int ldW_c = (t & 31) * 4;

    for (int kc = 0; kc < D; kc += KC) {
#pragma unroll
        for (int rr = 0; rr < BM; rr += 32) {
            int r = row0 + ldA_r + rr;
            int rcl = r < N ? r : N - 1;
            float4 v = *(const float4*)&io[(size_t)rcl * D + kc + ldA_k];
            sA[ldA_k + 0][ldA_r + rr] = v.x;
            sA[ldA_k + 1][ldA_r + rr] = v.y;
            sA[ldA_k + 2][ldA_r + rr] = v.z;
            sA[ldA_k + 3][ldA_r + rr] = v.w;
        }
#pragma unroll
        for (int kk = 0; kk < KC; kk += 8)
            *(float4*)&sW2[ldW_k + kk][ldW_c] =
                *(const float4*)&wt[(size_t)(kc + ldW_k + kk) * D + ldW_c];
        __syncthreads();

#pragma unroll 8
        for (int k = 0; k < KC; ++k) {
            float4 a = *(const float4*)&sA[k][tr * 4];
            float4 w0 = *(const float4*)&sW2[k][tc * 8];
            float4 w1 = *(const float4*)&sW2[k][tc * 8 + 4];
            float av[4] = {a.x, a.y, a.z, a.w};
            float wv[8] = {w0.x, w0.y, w0.z, w0.w, w1.x, w1.y, w1.z, w1.w};
#pragma unroll
            for (int i = 0; i < 4; ++i)
#pragma unroll
                for (int j = 0; j < 8; ++j)
                    acc[i][j] = fmaf(av[i], wv[j], acc[i][j]);
        }
        __syncthreads();
    }

#pragma unroll
    for (int i = 0; i < 4; ++i) {
        int r = row0 + tr * 4 + i;
        if (r < N) {
            *(float4*)&io[(size_t)r * D + tc * 8] = *(float4*)&acc[i][0];
            *(float4*)&io[(size_t)r * D + tc * 8 + 4] = *(float4*)&acc[i][4];
        }
    }
}

extern "C" void kernel_launch(void* const* d_in, const int* in_sizes, int n_in,
                              void* d_out, int out_size, void* d_ws, size_t ws_size,
                              hipStream_t stream) {
    const float* x = (const float*)d_in[0];
    const float* w = (const float*)d_in[1];
    const int* ei = (const int*)d_in[2];   // [2,E] int32 (dst row, then src row)
    const float* ev = (const float*)d_in[3];

    int N = in_sizes[0] / D;
    int E = in_sizes[3];
    int nblk = (N + SCAN_BLK - 1) / SCAN_BLK;
    int NB = (N + BNODES - 1) >> BSH;
    int nblkB = (NB + SCAN_BLK - 1) / SCAN_BLK;

    float* out = (float*)d_out;

    // workspace layout
    char* p = (char*)d_ws;
    float* wt = (float*)p;            p += (size_t)D * D * sizeof(float);
    unsigned short* wbfs = (unsigned short*)p;  p += (size_t)D * D * sizeof(unsigned short);
    int* deg = (int*)p;               p += (size_t)N * sizeof(int);
    int* inscan = (int*)p;            p += (size_t)N * sizeof(int);
    int* off = (int*)p;               p += (size_t)(N + 1) * sizeof(int);
    int* blksum = (int*)p;            p += (size_t)nblk * sizeof(int);
    int* blkoff = (int*)p;            p += (size_t)nblk * sizeof(int);
    p = (char*)(((uintptr_t)p + 255) & ~(uintptr_t)255);
    int* bhist = (int*)p;             p += (size_t)NB * sizeof(int);
    int* binscan = (int*)p;           p += (size_t)NB * sizeof(int);
    int* bbase = (int*)p;             p += (size_t)(NB + 1) * sizeof(int);
    int* bcursor = (int*)p;           p += (size_t)NB * sizeof(int);
    int* bblksum = (int*)p;           p += (size_t)(nblkB + 1) * sizeof(int);
    int* bblkoff = (int*)p;           p += (size_t)(nblkB + 1) * sizeof(int);
    p = (char*)(((uintptr_t)p + 255) & ~(uintptr_t)255);
    unsigned short* rank = (unsigned short*)p;  p += (size_t)E * sizeof(unsigned short);
    p = (char*)(((uintptr_t)p + 255) & ~(uintptr_t)255);
    int2* srt = (int2*)p;             p += (size_t)E * sizeof(int2);
    size_t needed_t2 = (size_t)(p - (char*)d_ws);
    p = (char*)(((uintptr_t)p + 255) & ~(uintptr_t)255);
    unsigned int* xbf = (unsigned int*)p;  p += (size_t)N * (D / 2) * sizeof(unsigned int);
    size_t needed_t1 = (size_t)(p - (char*)d_ws);
    p = (char*)(((uintptr_t)p + 255) & ~(uintptr_t)255);
    // union: ebin (alive binA..binB2) / aggbf (alive gather..linear)
    size_t ebin_bytes = (size_t)E * sizeof(int2);
    size_t aggbf_bytes = (size_t)N * (D / 2) * sizeof(unsigned int);
    int2* ebin = (int2*)p;
    unsigned int* aggbf = (unsigned int*)p;
    p += (ebin_bytes > aggbf_bytes ? ebin_bytes : aggbf_bytes);
    size_t needed_t0 = (size_t)(p - (char*)d_ws);

    if (ws_size >= needed_t0 && N < (1 << 26) && NB <= 2048) {
        // ---- binned CSR build: zero returning global atomics on the hot path ----
        prep_wbfs_kernel<<<(D * D + 255) / 256, 256, 0, stream>>>(w, wbfs);
        hipMemsetAsync(bhist, 0, (size_t)NB * sizeof(int), stream);
        x_to_bf16_kernel<<<2048, 256, 0, stream>>>(x, xbf, (long long)N * D / 4);
        bhist_kernel<<<200, 512, 0, stream>>>(ei, bhist, E, NB);
        scan_blocks_kernel<<<nblkB, SCAN_BLK, 0, stream>>>(bhist, binscan, bblksum, NB);
        scan_sums_kernel<<<1, 128, 0, stream>>>(bblksum, bblkoff, nblkB);
        bucket_finalize_kernel<<<(NB + 255) / 256, 256, 0, stream>>>(
            bhist, binscan, bblkoff, bbase, bcursor, off, NB, N, E);
        binA_kernel<<<(E + 8191) / 8192, 512, 0, stream>>>(ei, ev, bcursor, ebin, E, NB);
        binB2_kernel<<<NB, 512, 0, stream>>>(bbase, ebin, off, srt, N);
        gather_bf16_kernel<true><<<(N + 3) / 4, 256, 0, stream>>>(off, srt, xbf, out, aggbf, N);
        linear_mfma_bf2_kernel<<<(N + BM2 - 1) / BM2, 512, 0, stream>>>(aggbf, wbfs, out, N);
    } else if (ws_size >= needed_t1) {
        // ---- R10-proven fallback ----
        prep_wbfs_kernel<<<(D * D + 255) / 256, 256, 0, stream>>>(w, wbfs);
        hipMemsetAsync(deg, 0, (size_t)N * sizeof(int), stream);
        x_to_bf16_kernel<<<2048, 256, 0, stream>>>(x, xbf, (long long)N * D / 4);
        hist_rank_kernel<<<(E + 255) / 256, 256, 0, stream>>>(ei, deg, rank, E);
        scan_blocks_kernel<<<nblk, SCAN_BLK, 0, stream>>>(deg, inscan, blksum, N);
        scan_sums_kernel<<<1, 128, 0, stream>>>(blksum, blkoff, nblk);
        finalize_offsets_kernel<<<(N + 255) / 256, 256, 0, stream>>>(deg, inscan, blkoff,
                                                                     off, N, E);
        edge_scatter2_kernel<<<(E + 255) / 256, 256, 0, stream>>>(ei, ev, off, rank, srt, E);
        gather_bf16_kernel<false><<<(N + 3) / 4, 256, 0, stream>>>(off, srt, xbf, out,
                                                                   aggbf, N);
        linear_mfma_kernel<<<(N + BM - 1) / BM, 256, 0, stream>>>(out, wbfs, N);
    } else {
        transpose_w_kernel<<<(D * D + 255) / 256, 256, 0, stream>>>(w, wt);
        hipMemsetAsync(d_out, 0, (size_t)out_size * sizeof(float), stream);
        scatter_kernel<<<4096, 256, 0, stream>>>(ei, ev, x, out, E);
        linear_tiled_kernel<<<(N + BM - 1) / BM, 256, 0, stream>>>(out, wt, N);
    }
}

// Round 13
// 163.730 us; speedup vs baseline: 7.7226x; 1.0334x over previous
//
#include <hip/hip_runtime.h>

#define D 128
#define SCAN_BLK 1024
#define BM 64
#define BM2 128
#define KC 32
#define BSH 6
#define BNODES 64

using short8 = __attribute__((ext_vector_type(8))) short;
using floatx4 = __attribute__((ext_vector_type(4))) float;

__device__ __forceinline__ unsigned int f2bf(unsigned int b) {
    return (b + 0x7fffu + ((b >> 16) & 1u)) >> 16;  // RNE fp32->bf16 (as u16)
}

// ---------- W transpose (tier-3 VALU path) ----------
__global__ void transpose_w_kernel(const float* __restrict__ w, float* __restrict__ wt) {
    int t = blockIdx.x * 256 + threadIdx.x;
    if (t < D * D) {
        int o = t >> 7;
        int k = t & 127;
        wt[k * D + o] = w[t];
    }
}

// ---------- W -> bf16 swizzled table; also zeroes bhist (saves a memset launch) ----------
__global__ void prep_wbfs_kernel(const float* __restrict__ w, unsigned short* __restrict__ wbfs,
                                 int* bhist, int NB) {
    int t = blockIdx.x * 256 + threadIdx.x;
    if (t < D * D) {
        int n = t >> 7, k = t & 127;
        wbfs[n * 128 + (k ^ ((n & 7) << 3))] = (unsigned short)f2bf(__float_as_uint(w[t]));
    }
    for (int i = t; i < NB; i += gridDim.x * 256) bhist[i] = 0;
}

// ---------- fused: x->bf16 pair packing (blocks < xb)  +  bucket hist (blocks >= xb) ----------
__global__ __launch_bounds__(256) void x2bf_bhist_kernel(const float* __restrict__ x,
                                                         unsigned int* __restrict__ xbf,
                                                         long long nvec,
                                                         const int* __restrict__ ei,
                                                         int* bhist, int E, int NB, int xb) {
    __shared__ int h[2048];
    if ((int)blockIdx.x < xb) {
        long long i = (long long)blockIdx.x * 256 + threadIdx.x;
        long long stride = (long long)xb * 256;
        for (; i < nvec; i += stride) {
            float4 v = ((const float4*)x)[i];
            unsigned int b0 = f2bf(__float_as_uint(v.x)), b1 = f2bf(__float_as_uint(v.y));
            unsigned int b2 = f2bf(__float_as_uint(v.z)), b3 = f2bf(__float_as_uint(v.w));
            ((uint2*)xbf)[i] = make_uint2(b0 | (b1 << 16), b2 | (b3 << 16));
        }
    } else {
        int tid = threadIdx.x;
        for (int i = tid; i < NB; i += 256) h[i] = 0;
        __syncthreads();
        int hb = blockIdx.x - xb;
        int nhb = gridDim.x - xb;
        for (long long e = (long long)hb * 256 + tid; e < E; e += (long long)nhb * 256)
            atomicAdd(&h[((unsigned)ei[e]) >> BSH], 1);
        __syncthreads();
        for (int i = tid; i < NB; i += 256)
            if (h[i]) atomicAdd(&bhist[i], h[i]);
    }
}

// ---------- single-block bucket scan: bhist -> bbase/bcursor (+ off[N]=E) ----------
__global__ __launch_bounds__(1024) void bucket_scan_kernel(const int* __restrict__ bhist,
                                                           int* bbase, int* bcursor, int* off,
                                                           int NB, int N, int E) {
    __shared__ int s[1024];
    int t = threadIdx.x;
    int a = (2 * t < NB) ? bhist[2 * t] : 0;
    int b = (2 * t + 1 < NB) ? bhist[2 * t + 1] : 0;
    int sum = a + b;
    s[t] = sum;
    __syncthreads();
    for (int d = 1; d < 1024; d <<= 1) {
        int v = (t >= d) ? s[t - d] : 0;
        __syncthreads();
        s[t] += v;
        __syncthreads();
    }
    int excl = s[t] - sum;  // exclusive prefix of the pair
    if (2 * t < NB) { bbase[2 * t] = excl; bcursor[2 * t] = excl; }
    if (2 * t + 1 < NB) { bbase[2 * t + 1] = excl + a; bcursor[2 * t + 1] = excl + a; }
    if (t == 0) { bbase[NB] = E; off[N] = E; }
}

// ---------- binA: partition edges into 64-node buckets (order-free) ----------
__global__ __launch_bounds__(512) void binA_kernel(const int* __restrict__ ei,
                                                   const float* __restrict__ ev,
                                                   int* bcursor, int2* __restrict__ ebin,
                                                   int E, int NB) {
    __shared__ int hist[2048];
    __shared__ int base[2048];
    __shared__ int cnt2[2048];
    int tid = threadIdx.x;
    for (int i = tid; i < NB; i += 512) { hist[i] = 0; cnt2[i] = 0; }
    __syncthreads();
    int e0 = blockIdx.x * 8192;
#pragma unroll
    for (int i = 0; i < 16; ++i) {
        int e = e0 + i * 512 + tid;
        if (e < E) atomicAdd(&hist[((unsigned)ei[e]) >> BSH], 1);
    }
    __syncthreads();
    for (int i = tid; i < NB; i += 512)
        if (hist[i]) base[i] = atomicAdd(&bcursor[i], hist[i]);
    __syncthreads();
#pragma unroll
    for (int i = 0; i < 16; ++i) {
        int e = e0 + i * 512 + tid;
        if (e < E) {
            int dst = ei[e];
            int b = ((unsigned)dst) >> BSH;
            int pos = base[b] + atomicAdd(&cnt2[b], 1);
            ebin[pos] = make_int2(ei[E + e] | ((dst & (BNODES - 1)) << 26),
                                  __float_as_int(ev[e]));
        }
    }
}

// ---------- binB2: per-bucket exact CSR -> off + srt (LDS atomics only) ----------
__global__ __launch_bounds__(512) void binB2_kernel(const int* __restrict__ bbase,
                                                    const int2* __restrict__ ebin,
                                                    int* __restrict__ off,
                                                    int2* __restrict__ srt, int N) {
    __shared__ int degL[BNODES];
    __shared__ int cum[BNODES];
    __shared__ int cnt2[BNODES];
    int b = blockIdx.x;
    int tid = threadIdx.x;
    if (tid < BNODES) { degL[tid] = 0; cnt2[tid] = 0; }
    __syncthreads();
    int start = bbase[b], end = bbase[b + 1];
    for (int p = start + tid; p < end; p += 512)
        atomicAdd(&degL[((unsigned)ebin[p].x) >> 26], 1);
    __syncthreads();
    if (tid == 0) {
        int run = start;
#pragma unroll
        for (int i = 0; i < BNODES; ++i) { cum[i] = run; run += degL[i]; }
    }
    __syncthreads();
    int node0 = b << BSH;
    if (tid < BNODES && node0 + tid < N) off[node0 + tid] = cum[tid];
    for (int p = start + tid; p < end; p += 512) {
        int2 eb = ebin[p];
        int dl = ((unsigned)eb.x) >> 26;
        int pos = cum[dl] + atomicAdd(&cnt2[dl], 1);
        srt[pos] = make_int2(eb.x & 0x03FFFFFF, eb.y);
    }
}

// ---------- tier-2 fallback CSR machinery ----------
__global__ void hist_rank_kernel(const int* __restrict__ ei, int* deg,
                                 unsigned short* __restrict__ rank, int E) {
    int e = blockIdx.x * 256 + threadIdx.x;
    if (e < E) rank[e] = (unsigned short)atomicAdd(&deg[ei[e]], 1);
}

__global__ __launch_bounds__(SCAN_BLK) void scan_blocks_kernel(const int* __restrict__ deg,
                                                               int* inscan, int* blksum, int n) {
    __shared__ int s[SCAN_BLK];
    int gid = blockIdx.x * SCAN_BLK + threadIdx.x;
    int v = (gid < n) ? deg[gid] : 0;
    s[threadIdx.x] = v;
    __syncthreads();
    for (int d = 1; d < SCAN_BLK; d <<= 1) {
        int t = (threadIdx.x >= d) ? s[threadIdx.x - d] : 0;
        __syncthreads();
        s[threadIdx.x] += t;
        __syncthreads();
    }
    if (gid < n) inscan[gid] = s[threadIdx.x];
    if (threadIdx.x == SCAN_BLK - 1) blksum[blockIdx.x] = s[SCAN_BLK - 1];
}

__global__ __launch_bounds__(128) void scan_sums_kernel(const int* __restrict__ blksum,
                                                        int* blkoff, int nblk) {
    __shared__ int s[128];
    int v = (threadIdx.x < nblk) ? blksum[threadIdx.x] : 0;
    s[threadIdx.x] = v;
    __syncthreads();
    for (int d = 1; d < 128; d <<= 1) {
        int t = (threadIdx.x >= d) ? s[threadIdx.x - d] : 0;
        __syncthreads();
        s[threadIdx.x] += t;
        __syncthreads();
    }
    if (threadIdx.x < nblk) blkoff[threadIdx.x] = s[threadIdx.x] - v;
}

__global__ void finalize_offsets_kernel(const int* __restrict__ deg,
                                        const int* __restrict__ inscan,
                                        const int* __restrict__ blkoff,
                                        int* off, int n, int E) {
    int gid = blockIdx.x * 256 + threadIdx.x;
    if (gid < n) off[gid] = blkoff[gid >> 10] + inscan[gid] - deg[gid];
    if (gid == 0) off[n] = E;
}

__global__ void edge_scatter2_kernel(const int* __restrict__ ei, const float* __restrict__ ev,
                                     const int* __restrict__ off,
                                     const unsigned short* __restrict__ rank,
                                     int2* __restrict__ srt, int E) {
    int e = blockIdx.x * 256 + threadIdx.x;
    if (e < E) {
        int dst = ei[e];
        int pos = off[dst] + (int)rank[e];
        srt[pos] = make_int2(ei[E + e], __float_as_int(ev[e]));
    }
}

__global__ __launch_bounds__(256) void x_to_bf16_kernel(const float* __restrict__ x,
                                                        unsigned int* __restrict__ xbf,
                                                        long long nvec) {
    long long i = (long long)blockIdx.x * 256 + threadIdx.x;
    long long stride = (long long)gridDim.x * 256;
    for (; i < nvec; i += stride) {
        float4 v = ((const float4*)x)[i];
        unsigned int b0 = f2bf(__float_as_uint(v.x)), b1 = f2bf(__float_as_uint(v.y));
        unsigned int b2 = f2bf(__float_as_uint(v.z)), b3 = f2bf(__float_as_uint(v.w));
        ((uint2*)xbf)[i] = make_uint2(b0 | (b1 << 16), b2 | (b3 << 16));
    }
}

// ---------- CSR gather: 8-deep MLP + nontemporal srt stream; AGGBF packed out ----------
template <bool AGGBF>
__global__ __launch_bounds__(256) void gather_bf16_kernel(const int* __restrict__ off,
                                                          const int2* __restrict__ srt,
                                                          const unsigned int* __restrict__ xbf,
                                                          float* __restrict__ out,
                                                          unsigned int* __restrict__ aggbf,
                                                          int N) {
    int lane = threadIdx.x & 63;
    int wid = blockIdx.x * 4 + (threadIdx.x >> 6);
    if (wid >= N) return;
    int beg = off[wid], end = off[wid + 1];
    float2 acc = make_float2(0.f, 0.f);
    int e = beg;
    const unsigned long long* srt8 = (const unsigned long long*)srt;
    for (; e + 7 < end; e += 8) {
        unsigned long long q[8];
        unsigned int u[8];
#pragma unroll
        for (int j = 0; j < 8; ++j) q[j] = __builtin_nontemporal_load(&srt8[e + j]);
#pragma unroll
        for (int j = 0; j < 8; ++j)
            u[j] = xbf[(size_t)(unsigned int)q[j] * 64 + lane];
#pragma unroll
        for (int j = 0; j < 8; ++j) {
            float v = __uint_as_float((unsigned int)(q[j] >> 32));
            acc.x = fmaf(v, __uint_as_float(u[j] << 16), acc.x);
            acc.y = fmaf(v, __uint_as_float(u[j] & 0xffff0000u), acc.y);
        }
    }
    for (; e + 3 < end; e += 4) {
        unsigned long long q[4];
        unsigned int u[4];
#pragma unroll
        for (int j = 0; j < 4; ++j) q[j] = __builtin_nontemporal_load(&srt8[e + j]);
#pragma unroll
        for (int j = 0; j < 4; ++j)
            u[j] = xbf[(size_t)(unsigned int)q[j] * 64 + lane];
#pragma unroll
        for (int j = 0; j < 4; ++j) {
            float v = __uint_as_float((unsigned int)(q[j] >> 32));
            acc.x = fmaf(v, __uint_as_float(u[j] << 16), acc.x);
            acc.y = fmaf(v, __uint_as_float(u[j] & 0xffff0000u), acc.y);
        }
    }
    for (; e < end; ++e) {
        unsigned long long q = __builtin_nontemporal_load(&srt8[e]);
        unsigned int u = xbf[(size_t)(unsigned int)q * 64 + lane];
        float v = __uint_as_float((unsigned int)(q >> 32));
        acc.x = fmaf(v, __uint_as_float(u << 16), acc.x);
        acc.y = fmaf(v, __uint_as_float(u & 0xffff0000u), acc.y);
    }
    if (AGGBF) {
        unsigned int pk = f2bf(__float_as_uint(acc.x)) | (f2bf(__float_as_uint(acc.y)) << 16);
        aggbf[(size_t)wid * 64 + lane] = pk;
    } else {
        *(float2*)&out[(size_t)wid * D + lane * 2] = acc;
    }
}

// ---------- MFMA linear, BM2=128 rows/block, 8 waves, A from packed-bf16 agg ----------
__global__ __launch_bounds__(512) void linear_mfma_bf2_kernel(const unsigned int* __restrict__ aggbf,
                                                              const unsigned short* __restrict__ wbfs,
                                                              float* __restrict__ out, int N) {
    __shared__ __align__(16) unsigned short sW[D * D];
    __shared__ __align__(16) unsigned short sA[BM2 * D];
    int t = threadIdx.x;
    int row0 = blockIdx.x * BM2;
    {
        const uint4* src = (const uint4*)wbfs;
        uint4* dst = (uint4*)sW;
#pragma unroll
        for (int i = 0; i < 4; ++i) dst[i * 512 + t] = src[i * 512 + t];
    }
#pragma unroll
    for (int it = 0; it < 4; ++it) {
        int iv = it * 512 + t;
        int m = iv >> 4;
        int q = iv & 15;
        int r = row0 + m;
        int rcl = r < N ? r : N - 1;
        uint4 v = *(const uint4*)&aggbf[(size_t)rcl * 64 + q * 4];
        *(uint4*)((char*)sA + m * 256 + ((q * 16) ^ ((m & 7) << 4))) = v;
    }
    __syncthreads();

    int lane = t & 63;
    int w = t >> 6;
    int lm = 16 * w + (lane & 15);
    int ln = lane & 15;
    int kg = lane >> 4;

    floatx4 acc[8];
#pragma unroll
    for (int nt = 0; nt < 8; ++nt) acc[nt] = (floatx4){0.f, 0.f, 0.f, 0.f};

#pragma unroll
    for (int ks = 0; ks < 4; ++ks) {
        int kbyte = ks * 64 + kg * 16;
        short8 a = *(const short8*)((const char*)sA + lm * 256 + (kbyte ^ ((lm & 7) << 4)));
#pragma unroll
        for (int nt = 0; nt < 8; ++nt) {
            int n = nt * 16 + ln;
            short8 bfr = *(const short8*)((const char*)sW + n * 256 + (kbyte ^ ((n & 7) << 4)));
            acc[nt] = __builtin_amdgcn_mfma_f32_16x16x32_bf16(a, bfr, acc[nt], 0, 0, 0);
        }
    }

    int rbase = row0 + 16 * w + 4 * kg;
#pragma unroll
    for (int nt = 0; nt < 8; ++nt) {
#pragma unroll
        for (int r = 0; r < 4; ++r) {
            int row = rbase + r;
            if (row < N) out[(size_t)row * D + nt * 16 + ln] = acc[nt][r];
        }
    }
}

// ---------- MFMA linear in-place from fp32 io (tier-2 fallback) ----------
__global__ __launch_bounds__(256) void linear_mfma_kernel(float* io,
                                                          const unsigned short* __restrict__ wbfs,
                                                          int N) {
    __shared__ __align__(16) unsigned short sW[D * D];
    __shared__ __align__(16) unsigned short sA[BM * D];
    int t = threadIdx.x;
    int row0 = blockIdx.x * BM;
    {
        const uint4* src = (const uint4*)wbfs;
        uint4* dst = (uint4*)sW;
#pragma unroll
        for (int i = 0; i < 8; ++i) dst[i * 256 + t] = src[i * 256 + t];
    }
#pragma unroll
    for (int it = 0; it < 8; ++it) {
        int idx = it * 1024 + t * 4;
        int m = idx >> 7;
        int k0 = idx & 127;
        int r = row0 + m;
        int rcl = r < N ? r : N - 1;
        float4 v = *(const float4*)&io[(size_t)rcl * D + k0];
        unsigned int b0 = f2bf(__float_as_uint(v.x)), b1 = f2bf(__float_as_uint(v.y));
        unsigned int b2 = f2bf(__float_as_uint(v.z)), b3 = f2bf(__float_as_uint(v.w));
        int byteoff = m * 256 + ((k0 * 2) ^ ((m & 7) << 4));
        *(uint2*)((char*)sA + byteoff) = make_uint2(b0 | (b1 << 16), b2 | (b3 << 16));
    }
    __syncthreads();

    int lane = t & 63;
    int w = t >> 6;
    int lm = 16 * w + (lane & 15);
    int ln = lane & 15;
    int kg = lane >> 4;

    floatx4 acc[8];
#pragma unroll
    for (int nt = 0; nt < 8; ++nt) acc[nt] = (floatx4){0.f, 0.f, 0.f, 0.f};

#pragma unroll
    for (int ks = 0; ks < 4; ++ks) {
        int kbyte = ks * 64 + kg * 16;
        short8 a = *(const short8*)((const char*)sA + lm * 256 + (kbyte ^ ((lm & 7) << 4)));
#pragma unroll
        for (int nt = 0; nt < 8; ++nt) {
            int n = nt * 16 + ln;
            short8 bfr = *(const short8*)((const char*)sW + n * 256 + (kbyte ^ ((n & 7) << 4)));
            acc[nt] = __builtin_amdgcn_mfma_f32_16x16x32_bf16(a, bfr, acc[nt], 0, 0, 0);
        }
    }

    int rbase = row0 + 16 * w + 4 * kg;
#pragma unroll
    for (int nt = 0; nt < 8; ++nt) {
#pragma unroll
        for (int r = 0; r < 4; ++r) {
            int row = rbase + r;
            if (row < N) io[(size_t)row * D + nt * 16 + ln] = acc[nt][r];
        }
    }
}

// ---------- tier-3 fallbacks ----------
__global__ __launch_bounds__(256) void scatter_kernel(const int* __restrict__ ei,
                                                      const float* __restrict__ ev,
                                                      const float* __restrict__ x,
                                                      float* agg, int E) {
    int lane = threadIdx.x & 63;
    long long wid = (long long)blockIdx.x * 4 + (threadIdx.x >> 6);
    long long nw = (long long)gridDim.x * 4;
    for (long long e = wid; e < E; e += nw) {
        int i = ei[e];
        int j = ei[(long long)E + e];
        float v = ev[e];
        float2 xv = *(const float2*)&x[(size_t)j * D + lane * 2];
        float* op = &agg[(size_t)i * D + lane * 2];
        unsafeAtomicAdd(&op[0], v * xv.x);
        unsafeAtomicAdd(&op[1], v * xv.y);
    }
}

__global__ __launch_bounds__(256) void linear_tiled_kernel(float* io,
                                                           const float* __restrict__ wt,
                                                           int N) {
    __shared__ float sA[KC][BM + 4];
    __shared__ float sW2[KC][D];
    int t = threadIdx.x;
    int tc = t & 15;
    int tr = t >> 4;
    int row0 = blockIdx.x * BM;

    float acc[4][8];
#pragma unroll
    for (int i = 0; i < 4; ++i)
#pragma unroll
        for (int j = 0; j < 8; ++j) acc[i][j] = 0.f;

    int ldA_r = t >> 3;
    int ldA_k = (t & 7) * 4;
    int ldW_k = t >> 5;
    int ldW_c = (t & 31) * 4;

    for (int kc = 0; kc < D; kc += KC) {
#pragma unroll
        for (int rr = 0; rr < BM; rr += 32) {
            int r = row0 + ldA_r + rr;
            int rcl = r < N ? r : N - 1;
            float4 v = *(const float4*)&io[(size_t)rcl * D + kc + ldA_k];
            sA[ldA_k + 0][ldA_r + rr] = v.x;
            sA[ldA_k + 1][ldA_r + rr] = v.y;
            sA[ldA_k + 2][ldA_r + rr] = v.z;
            sA[ldA_k + 3][ldA_r + rr] = v.w;
        }
#pragma unroll
        for (int kk = 0; kk < KC; kk += 8)
            *(float4*)&sW2[ldW_k + kk][ldW_c] =
                *(const float4*)&wt[(size_t)(kc + ldW_k + kk) * D + ldW_c];
        __syncthreads();

#pragma unroll 8
        for (int k = 0; k < KC; ++k) {
            float4 a = *(const float4*)&sA[k][tr * 4];
            float4 w0 = *(const float4*)&sW2[k][tc * 8];
            float4 w1 = *(const float4*)&sW2[k][tc * 8 + 4];
            float av[4] = {a.x, a.y, a.z, a.w};
            float wv[8] = {w0.x, w0.y, w0.z, w0.w, w1.x, w1.y, w1.z, w1.w};
#pragma unroll
            for (int i = 0; i < 4; ++i)
#pragma unroll
                for (int j = 0; j < 8; ++j)
                    acc[i][j] = fmaf(av[i], wv[j], acc[i][j]);
        }
        __syncthreads();
    }

#pragma unroll
    for (int i = 0; i < 4; ++i) {
        int r = row0 + tr * 4 + i;
        if (r < N) {
            *(float4*)&io[(size_t)r * D + tc * 8] = *(float4*)&acc[i][0];
            *(float4*)&io[(size_t)r * D + tc * 8 + 4] = *(float4*)&acc[i][4];
        }
    }
}

extern "C" void kernel_launch(void* const* d_in, const int* in_sizes, int n_in,
                              void* d_out, int out_size, void* d_ws, size_t ws_size,
                              hipStream_t stream) {
    const float* x = (const float*)d_in[0];
    const float* w = (const float*)d_in[1];
    const int* ei = (const int*)d_in[2];   // [2,E] int32 (dst row, then src row)
    const float* ev = (const float*)d_in[3];

    int N = in_sizes[0] / D;
    int E = in_sizes[3];
    int nblk = (N + SCAN_BLK - 1) / SCAN_BLK;
    int NB = (N + BNODES - 1) >> BSH;

    float* out = (float*)d_out;

    // workspace layout
    char* p = (char*)d_ws;
    float* wt = (float*)p;            p += (size_t)D * D * sizeof(float);
    unsigned short* wbfs = (unsigned short*)p;  p += (size_t)D * D * sizeof(unsigned short);
    int* deg = (int*)p;               p += (size_t)N * sizeof(int);
    int* inscan = (int*)p;            p += (size_t)N * sizeof(int);
    int* off = (int*)p;               p += (size_t)(N + 1) * sizeof(int);
    int* blksum = (int*)p;            p += (size_t)nblk * sizeof(int);
    int* blkoff = (int*)p;            p += (size_t)nblk * sizeof(int);
    p = (char*)(((uintptr_t)p + 255) & ~(uintptr_t)255);
    int* bhist = (int*)p;             p += (size_t)NB * sizeof(int);
    int* bbase = (int*)p;             p += (size_t)(NB + 1) * sizeof(int);
    int* bcursor = (int*)p;           p += (size_t)NB * sizeof(int);
    p = (char*)(((uintptr_t)p + 255) & ~(uintptr_t)255);
    unsigned short* rank = (unsigned short*)p;  p += (size_t)E * sizeof(unsigned short);
    p = (char*)(((uintptr_t)p + 255) & ~(uintptr_t)255);
    int2* srt = (int2*)p;             p += (size_t)E * sizeof(int2);
    size_t needed_t2 = (size_t)(p - (char*)d_ws);
    p = (char*)(((uintptr_t)p + 255) & ~(uintptr_t)255);
    unsigned int* xbf = (unsigned int*)p;  p += (size_t)N * (D / 2) * sizeof(unsigned int);
    size_t needed_t1 = (size_t)(p - (char*)d_ws);
    p = (char*)(((uintptr_t)p + 255) & ~(uintptr_t)255);
    // union: ebin (alive binA..binB2) / aggbf (alive gather..linear)
    size_t ebin_bytes = (size_t)E * sizeof(int2);
    size_t aggbf_bytes = (size_t)N * (D / 2) * sizeof(unsigned int);
    int2* ebin = (int2*)p;
    unsigned int* aggbf = (unsigned int*)p;
    p += (ebin_bytes > aggbf_bytes ? ebin_bytes : aggbf_bytes);
    size_t needed_t0 = (size_t)(p - (char*)d_ws);

    if (ws_size >= needed_t0 && N < (1 << 26) && NB <= 2048) {
        // ---- binned CSR build: zero returning global atomics on the hot path ----
        const int xb = 1024, hb = 512;
        prep_wbfs_kernel<<<(D * D + 255) / 256, 256, 0, stream>>>(w, wbfs, bhist, NB);
        x2bf_bhist_kernel<<<xb + hb, 256, 0, stream>>>(x, xbf, (long long)N * D / 4,
                                                       ei, bhist, E, NB, xb);
        bucket_scan_kernel<<<1, 1024, 0, stream>>>(bhist, bbase, bcursor, off, NB, N, E);
        binA_kernel<<<(E + 8191) / 8192, 512, 0, stream>>>(ei, ev, bcursor, ebin, E, NB);
        binB2_kernel<<<NB, 512, 0, stream>>>(bbase, ebin, off, srt, N);
        gather_bf16_kernel<true><<<(N + 3) / 4, 256, 0, stream>>>(off, srt, xbf, out, aggbf, N);
        linear_mfma_bf2_kernel<<<(N + BM2 - 1) / BM2, 512, 0, stream>>>(aggbf, wbfs, out, N);
    } else if (ws_size >= needed_t1) {
        // ---- node-level CSR fallback ----
        prep_wbfs_kernel<<<(D * D + 255) / 256, 256, 0, stream>>>(w, wbfs, bhist, NB);
        hipMemsetAsync(deg, 0, (size_t)N * sizeof(int), stream);
        x_to_bf16_kernel<<<2048, 256, 0, stream>>>(x, xbf, (long long)N * D / 4);
        hist_rank_kernel<<<(E + 255) / 256, 256, 0, stream>>>(ei, deg, rank, E);
        scan_blocks_kernel<<<nblk, SCAN_BLK, 0, stream>>>(deg, inscan, blksum, N);
        scan_sums_kernel<<<1, 128, 0, stream>>>(blksum, blkoff, nblk);
        finalize_offsets_kernel<<<(N + 255) / 256, 256, 0, stream>>>(deg, inscan, blkoff,
                                                                     off, N, E);
        edge_scatter2_kernel<<<(E + 255) / 256, 256, 0, stream>>>(ei, ev, off, rank, srt, E);
        gather_bf16_kernel<false><<<(N + 3) / 4, 256, 0, stream>>>(off, srt, xbf, out,
                                                                   aggbf, N);
        linear_mfma_kernel<<<(N + BM - 1) / BM, 256, 0, stream>>>(out, wbfs, N);
    } else {
        transpose_w_kernel<<<(D * D + 255) / 256, 256, 0, stream>>>(w, wt);
        hipMemsetAsync(d_out, 0, (size_t)out_size * sizeof(float), stream);
        scatter_kernel<<<4096, 256, 0, stream>>>(ei, ev, x, out, E);
        linear_tiled_kernel<<<(N + BM - 1) / BM, 256, 0, stream>>>(out, wt, N);
    }
}